// Round 6
// baseline (1077.489 us; speedup 1.0000x reference)
//
#include <hip/hip_runtime.h>
#include <math.h>

typedef unsigned short u16;
typedef unsigned int u32;
typedef unsigned long long u64;

#define NSYN 37
#define NB   2048
#define KS   296
#define NIN  39
#define TSTEPS 2000
#define SFRAMES 200
#define HID 256
#define OUTC 39
#define NBLK 204          // LIN blocks alloc'd per chain (fw uses 200, bw 201, pad)

// ws layout (byte offsets, 16B aligned)
#define WS_WIT    0u          // float [2][39][2048] dense input weights (transposed)
#define WS_WSPK   638976u     // float [2][37][2048] spike-synapse weights
#define WS_OFFSPK 1245184u    // u16   [2][37][2048] spike LDS byte offsets
#define WS_CBIAS  1548288u    // float [2][2048]     raw bias
#define WS_BETA   1564672u    // float [2][2048]
#define WS_ALPHA  1581056u    // float [2][256]
#define WS_FRAMES 1583104u    // float [2][32][200][256]
#define WS_Y      14690304u   // float [200][32][39]
#define WS_LINH   15688704u   // u16/fp16 [64 chains][204 blocks][2048] commit-ordered

// ---------------------------------------------------------------- setup ----
__global__ void build_tables(
    const float* __restrict__ w_fw, const float* __restrict__ b_fw,
    const float* __restrict__ tau_n_fw, const float* __restrict__ mask_fw,
    const float* __restrict__ w_bw, const float* __restrict__ b_bw,
    const float* __restrict__ tau_n_bw, const float* __restrict__ mask_bw,
    const float* __restrict__ tau_m_fw, const float* __restrict__ tau_m_bw,
    float* __restrict__ WiT, float* __restrict__ Wspk, u16* __restrict__ OFFspk,
    float* __restrict__ CBIAS, float* __restrict__ BETA, float* __restrict__ ALPHA)
{
  const int rid = blockIdx.x * 256 + threadIdx.x;
  if (rid < 2 * NB) {
    const int dir = rid >> 11, r = rid & (NB - 1);
    const float* w  = dir ? w_bw : w_fw;
    const float* mk = dir ? mask_bw : mask_fw;
    const float* bb = dir ? b_bw : b_fw;
    const float* tn = dir ? tau_n_bw : tau_n_fw;
    float* wit = WiT + (size_t)dir * (NIN * NB);
    for (int c = 0; c < NIN; ++c) wit[c * NB + r] = 0.0f;
    int sc = 0;
    for (int j = 0; j < KS; ++j) {
      const float m = mk[(size_t)r * KS + j];
      if (m != 0.0f) {
        const float wv = w[(size_t)r * KS + j];
        if (j < NIN) {
          wit[j * NB + r] = wv;
        } else {
          // j==295 (pad) -> byte offset 256*4 = permanent-zero spike slot
          Wspk[(size_t)dir * (NSYN * NB) + (size_t)sc * NB + r]   = wv;
          OFFspk[(size_t)dir * (NSYN * NB) + (size_t)sc * NB + r] = (u16)((j - NIN) * 4);
          ++sc;
        }
      }
    }
    for (; sc < NSYN; ++sc) {
      Wspk[(size_t)dir * (NSYN * NB) + (size_t)sc * NB + r]   = 0.0f;
      OFFspk[(size_t)dir * (NSYN * NB) + (size_t)sc * NB + r] = (u16)(256 * 4);
    }
    BETA[dir * NB + r]  = 1.0f / (1.0f + expf(-tn[r]));
    CBIAS[dir * NB + r] = bb[r];
  }
  if (rid < 2 * HID) {
    const int dir = rid >> 8, h = rid & (HID - 1);
    const float* tm = dir ? tau_m_bw : tau_m_fw;
    ALPHA[rid] = 1.0f / (1.0f + expf(-tm[h]));
  }
}

// --------------------------------------------- per-frame input lin (fp16) ----
// LINH[chain][c][2048] in COMMIT order (fw: c->frame c; bw: c0->f0, c>=1 -> f(200-c)),
// chunk-permuted so scan lane l chunk ch holds branches l*32+ch*8..+7 at (ch*64+l)*8.
__global__ __launch_bounds__(256) void lin_precompute(
    const float* __restrict__ x, const float* __restrict__ WiT,
    const float* __restrict__ CBIAS, u16* __restrict__ LINH)
{
  const int bid = blockIdx.x;   // 0..400
  int dir, c, fr;
  if (bid < 200) { dir = 0; c = bid; fr = c; }
  else { dir = 1; c = bid - 200; fr = (c == 0) ? 0 : (200 - c); }
  const int t = threadIdx.x;
  const int r0 = t * 8;
  __shared__ float xs[32 * NIN];
  for (int i = t; i < 32 * NIN; i += 256) {
    const int b = i / NIN, cc = i - b * NIN;
    xs[i] = x[(size_t)b * (SFRAMES * NIN) + fr * NIN + cc];
  }
  __syncthreads();
  const float* wit = WiT + (size_t)dir * (NIN * NB) + r0;
  float bias[8];
  *reinterpret_cast<float4*>(&bias[0]) = *reinterpret_cast<const float4*>(CBIAS + dir * NB + r0);
  *reinterpret_cast<float4*>(&bias[4]) = *reinterpret_cast<const float4*>(CBIAS + dir * NB + r0 + 4);
  const int lpos = ((t & 3) * 64 + (t >> 2)) * 8;   // permuted half-offset
#pragma unroll 1
  for (int bt = 0; bt < 8; ++bt) {
    float acc[4][8];
#pragma unroll
    for (int q = 0; q < 4; ++q)
#pragma unroll
      for (int k = 0; k < 8; ++k) acc[q][k] = 0.0f;
#pragma unroll 1
    for (int cc = 0; cc < NIN; ++cc) {
      float wv[8];
      *reinterpret_cast<float4*>(&wv[0]) = *reinterpret_cast<const float4*>(wit + cc * NB);
      *reinterpret_cast<float4*>(&wv[4]) = *reinterpret_cast<const float4*>(wit + cc * NB + 4);
#pragma unroll
      for (int q = 0; q < 4; ++q) {
        const float sx = xs[(bt * 4 + q) * NIN + cc];
#pragma unroll
        for (int k = 0; k < 8; ++k) acc[q][k] += wv[k] * sx;
      }
    }
#pragma unroll
    for (int q = 0; q < 4; ++q) {
      const int b = bt * 4 + q;
      u16* dst = LINH + ((size_t)(dir * 32 + b) * NBLK + c) * NB + lpos;
      union { u16 h[8]; uint4 u; } pk;
#pragma unroll
      for (int k = 0; k < 8; ++k) {
        const _Float16 hv = (_Float16)(acc[q][k] + bias[k]);
        pk.h[k] = *reinterpret_cast<const u16*>(&hv);
      }
      *reinterpret_cast<uint4*>(dst) = pk.u;
    }
  }
}

// ------------------------------------------------------- recurrent core ----
__device__ __forceinline__ void gload_lds16(const void* g, void* l) {
  __builtin_amdgcn_global_load_lds(
      (const __attribute__((address_space(1))) void*)g,
      (__attribute__((address_space(3))) void*)l, 16, 0, 0);
}

// grid = 64 chains (dir*32 + b), block = 64 (ONE wave). Lane l owns neurons
// 4l..4l+3 (branches 32l..32l+31). State e = d - lin (so the silent step is
// e *= beta, and lin lives only as fp16 stream + per-neuron scalar sum Slin).
// No barriers: wave-synchronous; spike flag via __any.
__global__ __launch_bounds__(64, 1) void snn_scan(
    const u16* __restrict__ LINH, const float* __restrict__ Wspk,
    const u16* __restrict__ OFFspk, const float* __restrict__ BETA,
    const float* __restrict__ ALPHA, float* __restrict__ FRAMES)
{
  const int chain = blockIdx.x;
  const int dir = chain >> 5;
  const int l = threadIdx.x;

  __shared__ __align__(16) u16 ring[3][NB];   // lin fp16: old / new / incoming
  __shared__ __align__(16) float spkbuf[260]; // spikes; slots 256..259 stay 0

  // zero slot 2 (acts as "lin(-1)=0" for the first commit) and spike buffer
  {
    const float4 z4 = {0.f, 0.f, 0.f, 0.f};
    *reinterpret_cast<float4*>(&spkbuf[l * 4]) = z4;
    if (l == 0) *reinterpret_cast<float4*>(&spkbuf[256]) = z4;
    uint4* zz = reinterpret_cast<uint4*>(&ring[2][l * 32]);
    const uint4 zu = {0u, 0u, 0u, 0u};
    zz[0] = zu; zz[1] = zu; zz[2] = zu; zz[3] = zu;
  }

  // per-branch beta, per-neuron alpha
  float be[4][8];
#pragma unroll
  for (int q = 0; q < 4; ++q) {
    *reinterpret_cast<float4*>(&be[q][0]) =
        *reinterpret_cast<const float4*>(BETA + dir * NB + l * 32 + q * 8);
    *reinterpret_cast<float4*>(&be[q][4]) =
        *reinterpret_cast<const float4*>(BETA + dir * NB + l * 32 + q * 8 + 4);
  }
  float al[4], om[4];
#pragma unroll
  for (int q = 0; q < 4; ++q) {
    al[q] = ALPHA[dir * HID + l * 4 + q];
    om[q] = 1.0f - al[q];
  }

  const u16* LB = LINH + (size_t)chain * NBLK * NB;
  // prefetch blocks 0 and 1 into slots 0,1 (4 x 1KB chunks each)
#pragma unroll
  for (int i = 0; i < 4; ++i) {
    gload_lds16(LB + 0 * NB + i * 512 + l * 8, &ring[0][i * 512]);
    gload_lds16(LB + 1 * NB + i * 512 + l * 8, &ring[1][i * 512]);
  }

  float e[4][8];
#pragma unroll
  for (int q = 0; q < 4; ++q)
#pragma unroll
    for (int j = 0; j < 8; ++j) e[q][j] = 0.0f;
  float Sl[4] = {0.f, 0.f, 0.f, 0.f};
  float mem[4] = {0.f, 0.f, 0.f, 0.f};
  float sp[4] = {0.f, 0.f, 0.f, 0.f};
  float facc[4] = {0.f, 0.f, 0.f, 0.f};
  int F = 0;
  int c = 0;         // next commit block
  int m10 = 0;

  float* frow = FRAMES + (size_t)chain * (SFRAMES * HID) + l * 4;

#pragma unroll 1
  for (int st = 0; st < TSTEPS; ++st) {
    const bool commit = (dir == 0) ? (m10 == 0) : (st == 0 || m10 == 1);
    if (commit) {
      asm volatile("s_waitcnt vmcnt(0)" ::: "memory");   // prefetch landed
      const int sn = c % 3;                // new lin
      const int so = (c + 2) % 3;          // old lin (== c-1, slot2-zero for c=0)
      float lnew[4][8];
#pragma unroll
      for (int q = 0; q < 4; ++q) {
        const uint4 vn = *reinterpret_cast<const uint4*>(&ring[sn][(q * 64 + l) * 8]);
        const uint4 vo = *reinterpret_cast<const uint4*>(&ring[so][(q * 64 + l) * 8]);
        const _Float16* hn = reinterpret_cast<const _Float16*>(&vn);
        const _Float16* ho = reinterpret_cast<const _Float16*>(&vo);
#pragma unroll
        for (int j = 0; j < 8; ++j) {
          const float fn = (float)hn[j];
          e[q][j] += (float)ho[j] - fn;
          lnew[q][j] = fn;
        }
        Sl[q] = ((lnew[q][0] + lnew[q][1]) + (lnew[q][2] + lnew[q][3]))
              + ((lnew[q][4] + lnew[q][5]) + (lnew[q][6] + lnew[q][7]));
      }
      asm volatile("s_waitcnt lgkmcnt(0)" ::: "memory"); // reads done before overwrite
      const int st_tgt = (c + 2) % 3;      // overwrite the just-consumed old slot
#pragma unroll
      for (int i = 0; i < 4; ++i)
        gload_lds16(LB + (size_t)(c + 2) * NB + i * 512 + l * 8, &ring[st_tgt][i * 512]);
      ++c;
    }

    if (__builtin_expect(F, 0)) {
      // spikes live last step: exact per-branch gather from spike LDS
      const float* wsp = Wspk + (size_t)dir * (NSYN * NB) + l * 32;
      const u16*  ofp = OFFspk + (size_t)dir * (NSYN * NB) + l * 32;
      const char* kb = reinterpret_cast<const char*>(&spkbuf[0]);
      float sc[4][8];
#pragma unroll
      for (int q = 0; q < 4; ++q)
#pragma unroll
        for (int j = 0; j < 8; ++j) sc[q][j] = 0.0f;
#pragma unroll 1
      for (int s = 0; s < NSYN; ++s) {
#pragma unroll
        for (int q = 0; q < 4; ++q) {
          float wv[8];
          *reinterpret_cast<float4*>(&wv[0]) =
              *reinterpret_cast<const float4*>(wsp + (size_t)s * NB + q * 8);
          *reinterpret_cast<float4*>(&wv[4]) =
              *reinterpret_cast<const float4*>(wsp + (size_t)s * NB + q * 8 + 4);
          const uint4 ov = *reinterpret_cast<const uint4*>(ofp + (size_t)s * NB + q * 8);
          const u16* of = reinterpret_cast<const u16*>(&ov);
#pragma unroll
          for (int j = 0; j < 8; ++j)
            sc[q][j] += wv[j] * *reinterpret_cast<const float*>(kb + of[j]);
        }
      }
#pragma unroll
      for (int q = 0; q < 4; ++q)
#pragma unroll
        for (int j = 0; j < 8; ++j)
          e[q][j] = be[q][j] * e[q][j] + (1.0f - be[q][j]) * sc[q][j];
    } else {
      // silent: d = beta*d + (1-beta)*lin  <=>  e *= beta   (exact algebra)
#pragma unroll
      for (int q = 0; q < 4; ++q)
#pragma unroll
        for (int j = 0; j < 8; ++j) e[q][j] *= be[q][j];
    }

#pragma unroll
    for (int q = 0; q < 4; ++q) {
      const float esum = ((e[q][0] + e[q][1]) + (e[q][2] + e[q][3]))
                       + ((e[q][4] + e[q][5]) + (e[q][6] + e[q][7]));
      const float dsum = esum + Sl[q];
      mem[q] = fmaf(al[q], mem[q], fmaf(om[q], dsum, -sp[q]));
      sp[q] = (mem[q] > 1.0f) ? 1.0f : 0.0f;
      facc[q] += sp[q];
    }

    // publish spikes (in-wave, no barrier needed)
    {
      const float4 sv = {sp[0], sp[1], sp[2], sp[3]};
      *reinterpret_cast<float4*>(&spkbuf[l * 4]) = sv;
    }
    F = __any((sp[0] + sp[1] + sp[2] + sp[3]) > 0.0f);

    if (m10 == 9) {
      const float4 fv = {facc[0] * 0.1f, facc[1] * 0.1f, facc[2] * 0.1f, facc[3] * 0.1f};
      *reinterpret_cast<float4*>(frow + (st / 10) * HID) = fv;
      facc[0] = facc[1] = facc[2] = facc[3] = 0.0f;
      m10 = 0;
    } else {
      ++m10;
    }
  }
}

// ------------------------------------------------------------- readout ----
// grid = 400 (s*2 + half), 16 batches per block staged in LDS; 256 threads,
// thread (bb,oc) computes outs oc, oc+16, oc+32 for batch b0+bb.
__global__ __launch_bounds__(256) void ro_matmul(
    const float* __restrict__ FRAMES, const float* __restrict__ w_ro,
    const float* __restrict__ b_ro, float* __restrict__ Y)
{
  const int bid = blockIdx.x;
  const int s = bid >> 1, b0 = (bid & 1) * 16;
  __shared__ float row[16][513];
  for (int i = threadIdx.x; i < 16 * 512; i += 256) {
    const int bb = i >> 9, k = i & 511;
    float v;
    if (k < 256) v = FRAMES[((size_t)(b0 + bb) * SFRAMES + s) * HID + k];
    else         v = FRAMES[((size_t)(32 + b0 + bb) * SFRAMES + (199 - s)) * HID + (k - 256)];
    row[bb][k] = v;
  }
  __syncthreads();
  const int bb = threadIdx.x >> 4;
  const int oc = threadIdx.x & 15;
  const int o1 = oc + 16, o2 = oc + 32;
  float a0 = 0.f, a1 = 0.f, a2 = 0.f;
  const float* w0 = w_ro + (size_t)oc * 512;
  const float* w1 = w_ro + (size_t)o1 * 512;
  const float* w2 = w_ro + (size_t)o2 * 512;
#pragma unroll 4
  for (int k = 0; k < 512; ++k) {
    const float rv = row[bb][k];
    a0 += rv * w0[k];
    if (o1 < OUTC) a1 += rv * w1[k];
    if (o2 < OUTC) a2 += rv * w2[k];
  }
  float* yp = Y + ((size_t)s * 32 + b0 + bb) * OUTC;
  yp[oc] = a0 + b_ro[oc];
  if (o1 < OUTC) yp[o1] = a1 + b_ro[o1];
  if (o2 < OUTC) yp[o2] = a2 + b_ro[o2];
}

__global__ void ro_scan(const float* __restrict__ Y,
                        const float* __restrict__ tau_ro,
                        const int* __restrict__ labels,
                        float* __restrict__ out)
{
  const int b = blockIdx.x;            // 32 blocks
  const int o = threadIdx.x;           // 64 threads
  __shared__ float mems[SFRAMES * 40];
  if (o < OUTC) {
    const float ar = 1.0f / (1.0f + expf(-tau_ro[o]));
    const float om = 1.0f - ar;
    float m = 0.0f;
    for (int s = 0; s < SFRAMES; ++s) {
      m = ar * m + om * Y[((size_t)s * 32 + b) * OUTC + o];
      mems[s * 40 + o] = m;
    }
  }
  __syncthreads();
  for (int s = threadIdx.x; s < SFRAMES; s += 64) {
    float mx = -1e30f;
    for (int j = 0; j < OUTC; ++j) mx = fmaxf(mx, mems[s * 40 + j]);
    float se = 0.0f;
    for (int j = 0; j < OUTC; ++j) se += expf(mems[s * 40 + j] - mx);
    const float lse = logf(se);
    float* op = out + ((size_t)s * 32 + b) * OUTC;
    for (int j = 0; j < OUTC; ++j) op[j] = mems[s * 40 + j] - mx - lse;
    const int lab = labels[b * SFRAMES + s];
    const float nll = -(mems[s * 40 + lab] - mx - lse);
    atomicAdd(out + SFRAMES * 32 * OUTC, nll * (1.0f / 32.0f));
  }
}

// -------------------------------------------------------------- launch ----
extern "C" void kernel_launch(void* const* d_in, const int* in_sizes, int n_in,
                              void* d_out, int out_size, void* d_ws, size_t ws_size,
                              hipStream_t stream)
{
  const float* x        = (const float*)d_in[0];
  const int*   labels   = (const int*)d_in[1];
  const float* w_fw     = (const float*)d_in[2];
  const float* b_fw     = (const float*)d_in[3];
  const float* tau_m_fw = (const float*)d_in[4];
  const float* tau_n_fw = (const float*)d_in[5];
  const float* mask_fw  = (const float*)d_in[6];
  const float* w_bw     = (const float*)d_in[7];
  const float* b_bw     = (const float*)d_in[8];
  const float* tau_m_bw = (const float*)d_in[9];
  const float* tau_n_bw = (const float*)d_in[10];
  const float* mask_bw  = (const float*)d_in[11];
  const float* w_ro     = (const float*)d_in[12];
  const float* b_ro     = (const float*)d_in[13];
  const float* tau_m_ro = (const float*)d_in[14];
  float* out = (float*)d_out;

  char* ws = (char*)d_ws;
  float* WiT    = (float*)(ws + WS_WIT);
  float* Wspk   = (float*)(ws + WS_WSPK);
  u16*   OFFspk = (u16*)(ws + WS_OFFSPK);
  float* CBIAS  = (float*)(ws + WS_CBIAS);
  float* BETA   = (float*)(ws + WS_BETA);
  float* ALPHA  = (float*)(ws + WS_ALPHA);
  float* FRAMES = (float*)(ws + WS_FRAMES);
  float* Y      = (float*)(ws + WS_Y);
  u16*   LINH   = (u16*)(ws + WS_LINH);

  hipMemsetAsync(out + SFRAMES * 32 * OUTC, 0, sizeof(float), stream);

  build_tables<<<16, 256, 0, stream>>>(w_fw, b_fw, tau_n_fw, mask_fw,
                                       w_bw, b_bw, tau_n_bw, mask_bw,
                                       tau_m_fw, tau_m_bw,
                                       WiT, Wspk, OFFspk, CBIAS, BETA, ALPHA);
  lin_precompute<<<401, 256, 0, stream>>>(x, WiT, CBIAS, LINH);
  snn_scan<<<64, 64, 0, stream>>>(LINH, Wspk, OFFspk, BETA, ALPHA, FRAMES);
  ro_matmul<<<2 * SFRAMES, 256, 0, stream>>>(FRAMES, w_ro, b_ro, Y);
  ro_scan<<<32, 64, 0, stream>>>(Y, tau_m_ro, labels, out);
}

// Round 7
// 641.661 us; speedup vs baseline: 1.6792x; 1.6792x over previous
//
#include <hip/hip_runtime.h>
#include <math.h>

typedef unsigned short u16;
typedef unsigned int u32;
typedef unsigned long long u64;
typedef float v2f __attribute__((ext_vector_type(2)));

#define NSYN 37
#define NB   2048
#define KS   296
#define NIN  39
#define TSTEPS 2000
#define SFRAMES 200
#define HID 256
#define OUTC 39
#define NBLK 204          // LIN blocks alloc'd per chain (fw uses 200, bw 201, pad)

// ws layout (byte offsets, 16B aligned)
#define WS_WIT    0u          // float [2][39][2048] dense input weights (transposed)
#define WS_WSPK   638976u     // float [2][37][2048] spike-synapse weights
#define WS_OFFSPK 1245184u    // u16   [2][37][2048] spike LDS byte offsets
#define WS_CBIAS  1548288u    // float [2][2048]     raw bias
#define WS_BETA   1564672u    // float [2][2048]
#define WS_ALPHA  1581056u    // float [2][256]
#define WS_FRAMES 1583104u    // float [2][32][200][256]
#define WS_Y      14690304u   // float [200][32][39]
#define WS_LINH   15688704u   // u16/fp16 [64 chains][204 blocks][2048] commit-ordered

#define VMW0() asm volatile("s_waitcnt vmcnt(0)" ::: "memory")

// ---------------------------------------------------------------- setup ----
// one WAVE per (dir,row): coalesced mask reads + ballot compaction
__global__ __launch_bounds__(256) void build_tables(
    const float* __restrict__ w_fw, const float* __restrict__ b_fw,
    const float* __restrict__ tau_n_fw, const float* __restrict__ mask_fw,
    const float* __restrict__ w_bw, const float* __restrict__ b_bw,
    const float* __restrict__ tau_n_bw, const float* __restrict__ mask_bw,
    const float* __restrict__ tau_m_fw, const float* __restrict__ tau_m_bw,
    float* __restrict__ WiT, float* __restrict__ Wspk, u16* __restrict__ OFFspk,
    float* __restrict__ CBIAS, float* __restrict__ BETA, float* __restrict__ ALPHA)
{
  const int row = blockIdx.x * 4 + (threadIdx.x >> 6);   // 0..4095
  const int l = threadIdx.x & 63;
  const int dir = row >> 11, r = row & (NB - 1);
  const float* w  = dir ? w_bw : w_fw;
  const float* mk = dir ? mask_bw : mask_fw;
  float* wit = WiT + (size_t)dir * (NIN * NB);
  float* wsp = Wspk + (size_t)dir * (NSYN * NB);
  u16*   osp = OFFspk + (size_t)dir * (NSYN * NB);
  const u64 ltm = (1ull << l) - 1ull;
  int sc = 0;
#pragma unroll
  for (int ch = 0; ch < 5; ++ch) {
    const int j = ch * 64 + l;
    const float m = (j < KS) ? mk[(size_t)r * KS + j] : 0.0f;
    const u64 bits = __ballot(m != 0.0f);
    const u64 sbits = (ch == 0) ? ((bits >> NIN) << NIN) : bits;  // entries j>=39
    if (m != 0.0f) {
      const float wv = w[(size_t)r * KS + j];
      if (j < NIN) {
        wit[(size_t)j * NB + r] = wv;
      } else {
        const int pos = sc + (int)__popcll(sbits & ltm);
        if (pos < NSYN) {
          wsp[(size_t)pos * NB + r] = wv;
          osp[(size_t)pos * NB + r] = (u16)((j - NIN) * 4);
        }
      }
    }
    sc += (int)__popcll(sbits);
  }
  for (int p = sc + l; p < NSYN; p += 64) {   // pad -> permanent-zero slot
    wsp[(size_t)p * NB + r] = 0.0f;
    osp[(size_t)p * NB + r] = (u16)(256 * 4);
  }
  if (l == 0) {
    const float* tn = dir ? tau_n_bw : tau_n_fw;
    const float* bb = dir ? b_bw : b_fw;
    BETA[dir * NB + r]  = 1.0f / (1.0f + expf(-tn[r]));
    CBIAS[dir * NB + r] = bb[r];
    if (r < HID) {
      const float* tm = dir ? tau_m_bw : tau_m_fw;
      ALPHA[dir * HID + r] = 1.0f / (1.0f + expf(-tm[r]));
    }
  }
}

// --------------------------------------------- per-frame input lin (fp16) ----
// LINH[chain][c][2048] in COMMIT order (fw: c->frame c; bw: c0->f0, c>=1 -> f(200-c)),
// chunk-permuted so scan lane l chunk q holds branches l*32+q*8..+7 at (q*64+l)*8.
__global__ __launch_bounds__(256) void lin_precompute(
    const float* __restrict__ x, const float* __restrict__ WiT,
    const float* __restrict__ CBIAS, u16* __restrict__ LINH)
{
  const int bid = blockIdx.x;   // 0..400
  int dir, c, fr;
  if (bid < 200) { dir = 0; c = bid; fr = c; }
  else { dir = 1; c = bid - 200; fr = (c == 0) ? 0 : (200 - c); }
  const int t = threadIdx.x;
  const int r0 = t * 8;
  __shared__ float xs[32 * NIN];
  for (int i = t; i < 32 * NIN; i += 256) {
    const int b = i / NIN, cc = i - b * NIN;
    xs[i] = x[(size_t)b * (SFRAMES * NIN) + fr * NIN + cc];
  }
  __syncthreads();
  const float* wit = WiT + (size_t)dir * (NIN * NB) + r0;
  float bias[8];
  *reinterpret_cast<float4*>(&bias[0]) = *reinterpret_cast<const float4*>(CBIAS + dir * NB + r0);
  *reinterpret_cast<float4*>(&bias[4]) = *reinterpret_cast<const float4*>(CBIAS + dir * NB + r0 + 4);
  const int lpos = ((t & 3) * 64 + (t >> 2)) * 8;   // permuted offset
#pragma unroll 1
  for (int bt = 0; bt < 8; ++bt) {
    float acc[4][8];
#pragma unroll
    for (int q = 0; q < 4; ++q)
#pragma unroll
      for (int k = 0; k < 8; ++k) acc[q][k] = 0.0f;
#pragma unroll 1
    for (int cc = 0; cc < NIN; ++cc) {
      float wv[8];
      *reinterpret_cast<float4*>(&wv[0]) = *reinterpret_cast<const float4*>(wit + cc * NB);
      *reinterpret_cast<float4*>(&wv[4]) = *reinterpret_cast<const float4*>(wit + cc * NB + 4);
#pragma unroll
      for (int q = 0; q < 4; ++q) {
        const float sx = xs[(bt * 4 + q) * NIN + cc];
#pragma unroll
        for (int k = 0; k < 8; ++k) acc[q][k] += wv[k] * sx;
      }
    }
#pragma unroll
    for (int q = 0; q < 4; ++q) {
      const int b = bt * 4 + q;
      u16* dst = LINH + ((size_t)(dir * 32 + b) * NBLK + c) * NB + lpos;
      union { u16 h[8]; uint4 u; } pk;
#pragma unroll
      for (int k = 0; k < 8; ++k) {
        const _Float16 hv = (_Float16)(acc[q][k] + bias[k]);
        pk.h[k] = *reinterpret_cast<const u16*>(&hv);
      }
      *reinterpret_cast<uint4*>(dst) = pk.u;
    }
  }
}

// ------------------------------------------------------- recurrent core ----
__device__ __forceinline__ void gload_lds16(const void* g, void* l) {
  __builtin_amdgcn_global_load_lds(
      (const __attribute__((address_space(1))) void*)g,
      (__attribute__((address_space(3))) void*)l, 16, 0, 0);
}

// grid = 64 chains (dir*32 + b), block = 64 (ONE wave). Lane l owns neurons
// 4l..4l+3 (branches 32l..32l+31), state e = d - lin. Window (frame) structure:
// fast path = 10 straight-line silent steps + one spike-certification __any;
// bitwise-identical to the slow path's silent branch, so no guard band needed.
// Slow path (spikes live / certification failed): restore window-start state,
// re-run the window with per-step gathers+publishes.
__global__ __launch_bounds__(64, 1) void snn_scan(
    const u16* __restrict__ LINH, const float* __restrict__ Wspk,
    const u16* __restrict__ OFFspk, const float* __restrict__ BETA,
    const float* __restrict__ ALPHA, float* __restrict__ FRAMES)
{
  const int chain = blockIdx.x;
  const int dir = chain >> 5;
  const int l = threadIdx.x;

  __shared__ __align__(16) u16 ring[4][NB];   // lin fp16 4-slot ring
  __shared__ __align__(16) float spkbuf[260]; // spikes; slots 256..259 stay 0

  {
    const float4 z4 = {0.f, 0.f, 0.f, 0.f};
    *reinterpret_cast<float4*>(&spkbuf[l * 4]) = z4;
    if (l == 0) *reinterpret_cast<float4*>(&spkbuf[256]) = z4;
    const uint4 zu = {0u, 0u, 0u, 0u};
    uint4* zz = reinterpret_cast<uint4*>(&ring[3][l * 32]);   // lin(-1) = 0
    zz[0] = zu; zz[1] = zu; zz[2] = zu; zz[3] = zu;
  }

  v2f e2[4][4], be2[4][4];
  float Sl[4] = {0.f, 0.f, 0.f, 0.f};
  float mem[4] = {0.f, 0.f, 0.f, 0.f};
  float sp[4] = {0.f, 0.f, 0.f, 0.f};
  float al[4], om[4];
#pragma unroll
  for (int q = 0; q < 4; ++q) {
    const v2f* bp = reinterpret_cast<const v2f*>(BETA + dir * NB + l * 32 + q * 8);
#pragma unroll
    for (int i = 0; i < 4; ++i) { be2[q][i] = bp[i]; e2[q][i] = (v2f){0.f, 0.f}; }
    al[q] = ALPHA[dir * HID + l * 4 + q];
    om[q] = 1.0f - al[q];
  }

  const u16* LB = LINH + (size_t)chain * NBLK * NB;
#pragma unroll
  for (int i = 0; i < 4; ++i) {
    gload_lds16(LB + 0 * NB + i * 512 + l * 8, &ring[0][i * 512]);
    gload_lds16(LB + 1 * NB + i * 512 + l * 8, &ring[1][i * 512]);
  }

  const float* wsp = Wspk + (size_t)dir * (NSYN * NB) + l * 32;
  const u16*  ofp = OFFspk + (size_t)dir * (NSYN * NB) + l * 32;
  float* frow = FRAMES + (size_t)chain * (SFRAMES * HID) + l * 4;

  int F = 0, c = 0;
  float mmax[4], facc[4];
  float4 pend = {0.f, 0.f, 0.f, 0.f};

  auto tree8 = [](const v2f v[4]) -> float {
    const v2f a = v[0] + v[1];
    const v2f b = v[2] + v[3];
    const v2f t = a + b;
    return t.x + t.y;
  };

  auto commit = [&](bool dopref) {
    const int sn = c & 3, so = (c + 3) & 3;
#pragma unroll
    for (int q = 0; q < 4; ++q) {
      const uint4 vn = *reinterpret_cast<const uint4*>(&ring[sn][(q * 64 + l) * 8]);
      const uint4 vo = *reinterpret_cast<const uint4*>(&ring[so][(q * 64 + l) * 8]);
      const _Float16* hn = reinterpret_cast<const _Float16*>(&vn);
      const _Float16* ho = reinterpret_cast<const _Float16*>(&vo);
      v2f ln2[4];
#pragma unroll
      for (int i = 0; i < 4; ++i) {
        const float fn0 = (float)hn[2 * i], fn1 = (float)hn[2 * i + 1];
        v2f dd; dd.x = (float)ho[2 * i] - fn0; dd.y = (float)ho[2 * i + 1] - fn1;
        e2[q][i] += dd;
        ln2[i].x = fn0; ln2[i].y = fn1;
      }
      Sl[q] = tree8(ln2);
    }
    if (dopref) {                       // prefetch 2 blocks ahead; slot disjoint
      const u16* src = LB + (size_t)(c + 2) * NB;
      u16* dst = &ring[(c + 2) & 3][0];
#pragma unroll
      for (int i = 0; i < 4; ++i)
        gload_lds16(src + i * 512 + l * 8, dst + i * 512);
    }
    ++c;
  };

  auto fstep = [&]() {
#pragma unroll
    for (int q = 0; q < 4; ++q)
#pragma unroll
      for (int i = 0; i < 4; ++i) e2[q][i] *= be2[q][i];
#pragma unroll
    for (int q = 0; q < 4; ++q) {
      const float esum = tree8(e2[q]);
      const float dsum = esum + Sl[q];
      mem[q] = fmaf(al[q], mem[q], fmaf(om[q], dsum, -sp[q]));
      mmax[q] = fmaxf(mmax[q], mem[q]);
    }
  };

  auto sstep = [&]() {
    if (__builtin_expect(F, 0)) {       // spikes live: exact gather
      float scv[4][8];
#pragma unroll
      for (int q = 0; q < 4; ++q)
#pragma unroll
        for (int j = 0; j < 8; ++j) scv[q][j] = 0.0f;
      const char* kb = reinterpret_cast<const char*>(&spkbuf[0]);
#pragma unroll 1
      for (int s = 0; s < NSYN; ++s) {
#pragma unroll
        for (int q = 0; q < 4; ++q) {
          float wv[8];
          *reinterpret_cast<float4*>(&wv[0]) =
              *reinterpret_cast<const float4*>(wsp + (size_t)s * NB + q * 8);
          *reinterpret_cast<float4*>(&wv[4]) =
              *reinterpret_cast<const float4*>(wsp + (size_t)s * NB + q * 8 + 4);
          const uint4 ov = *reinterpret_cast<const uint4*>(ofp + (size_t)s * NB + q * 8);
          const u16* of = reinterpret_cast<const u16*>(&ov);
#pragma unroll
          for (int j = 0; j < 8; ++j)
            scv[q][j] += wv[j] * *reinterpret_cast<const float*>(kb + of[j]);
        }
      }
#pragma unroll
      for (int q = 0; q < 4; ++q)
#pragma unroll
        for (int i = 0; i < 4; ++i) {
          v2f sc2; sc2.x = scv[q][2 * i]; sc2.y = scv[q][2 * i + 1];
          const v2f one = {1.0f, 1.0f};
          e2[q][i] = be2[q][i] * e2[q][i] + (one - be2[q][i]) * sc2;
        }
    } else {                            // silent: identical to fstep core
#pragma unroll
      for (int q = 0; q < 4; ++q)
#pragma unroll
        for (int i = 0; i < 4; ++i) e2[q][i] *= be2[q][i];
    }
    float ssum = 0.0f;
#pragma unroll
    for (int q = 0; q < 4; ++q) {
      const float esum = tree8(e2[q]);
      const float dsum = esum + Sl[q];
      mem[q] = fmaf(al[q], mem[q], fmaf(om[q], dsum, -sp[q]));
      sp[q] = (mem[q] > 1.0f) ? 1.0f : 0.0f;
      facc[q] += sp[q];
      ssum += sp[q];
    }
    const float4 sv = {sp[0], sp[1], sp[2], sp[3]};
    *reinterpret_cast<float4*>(&spkbuf[l * 4]) = sv;
    F = __any(ssum > 0.0f);
  };

#pragma unroll 1
  for (int w = 0; w < SFRAMES; ++w) {
    // save window-start state for possible slow redo
    v2f es[4][4]; float Sls[4], mems_[4], sps[4];
#pragma unroll
    for (int q = 0; q < 4; ++q) {
#pragma unroll
      for (int i = 0; i < 4; ++i) es[q][i] = e2[q][i];
      Sls[q] = Sl[q]; mems_[q] = mem[q]; sps[q] = sp[q];
    }
    const int cs = c;
    bool slow = (F != 0);
    bool prefed = false;

    if (!slow) {
      prefed = true;
      mmax[0] = mmax[1] = mmax[2] = mmax[3] = -1e30f;
      if (dir == 0) {
        VMW0(); commit(true);
        if (w) *reinterpret_cast<float4*>(frow + (w - 1) * HID) = pend;
#pragma unroll
        for (int t = 0; t < 10; ++t) fstep();
      } else {
        if (w == 0) { VMW0(); commit(true); }
        fstep();
        VMW0(); commit(true);
        if (w) *reinterpret_cast<float4*>(frow + (w - 1) * HID) = pend;
#pragma unroll
        for (int t = 0; t < 9; ++t) fstep();
      }
      const int viol = (mmax[0] > 1.0f) || (mmax[1] > 1.0f) ||
                       (mmax[2] > 1.0f) || (mmax[3] > 1.0f);
      slow = (__any(viol) != 0);
      if (!slow) {
        pend = (float4){0.f, 0.f, 0.f, 0.f};   // facc = 0 exactly
      } else {                                  // restore + redo
#pragma unroll
        for (int q = 0; q < 4; ++q) {
#pragma unroll
          for (int i = 0; i < 4; ++i) e2[q][i] = es[q][i];
          Sl[q] = Sls[q]; mem[q] = mems_[q]; sp[q] = sps[q];
        }
        c = cs;
      }
    }
    if (slow) {
      facc[0] = facc[1] = facc[2] = facc[3] = 0.0f;
      if (dir == 0) {
        VMW0(); commit(!prefed);
        if (w) *reinterpret_cast<float4*>(frow + (w - 1) * HID) = pend;
#pragma unroll 1
        for (int t = 0; t < 10; ++t) sstep();
      } else {
        if (w == 0) { VMW0(); commit(!prefed); }
        sstep();
        VMW0(); commit(!prefed);
        if (w) *reinterpret_cast<float4*>(frow + (w - 1) * HID) = pend;
#pragma unroll 1
        for (int t = 0; t < 9; ++t) sstep();
      }
      pend = (float4){facc[0] * 0.1f, facc[1] * 0.1f, facc[2] * 0.1f, facc[3] * 0.1f};
    }
  }
  *reinterpret_cast<float4*>(frow + (SFRAMES - 1) * HID) = pend;
}

// ------------------------------------------------------------- readout ----
__global__ __launch_bounds__(256) void ro_matmul(
    const float* __restrict__ FRAMES, const float* __restrict__ w_ro,
    const float* __restrict__ b_ro, float* __restrict__ Y)
{
  const int bid = blockIdx.x;
  const int s = bid >> 1, b0 = (bid & 1) * 16;
  __shared__ float row[16][513];
  for (int i = threadIdx.x; i < 16 * 512; i += 256) {
    const int bb = i >> 9, k = i & 511;
    float v;
    if (k < 256) v = FRAMES[((size_t)(b0 + bb) * SFRAMES + s) * HID + k];
    else         v = FRAMES[((size_t)(32 + b0 + bb) * SFRAMES + (199 - s)) * HID + (k - 256)];
    row[bb][k] = v;
  }
  __syncthreads();
  const int bb = threadIdx.x >> 4;
  const int oc = threadIdx.x & 15;
  const int o1 = oc + 16, o2 = oc + 32;
  float a0 = 0.f, a1 = 0.f, a2 = 0.f;
  const float* w0 = w_ro + (size_t)oc * 512;
  const float* w1 = w_ro + (size_t)o1 * 512;
  const float* w2 = w_ro + (size_t)o2 * 512;
#pragma unroll 4
  for (int k = 0; k < 512; ++k) {
    const float rv = row[bb][k];
    a0 += rv * w0[k];
    if (o1 < OUTC) a1 += rv * w1[k];
    if (o2 < OUTC) a2 += rv * w2[k];
  }
  float* yp = Y + ((size_t)s * 32 + b0 + bb) * OUTC;
  yp[oc] = a0 + b_ro[oc];
  if (o1 < OUTC) yp[o1] = a1 + b_ro[o1];
  if (o2 < OUTC) yp[o2] = a2 + b_ro[o2];
}

__global__ __launch_bounds__(256) void ro_scan(
    const float* __restrict__ Y, const float* __restrict__ tau_ro,
    const int* __restrict__ labels, float* __restrict__ out)
{
  const int b = blockIdx.x;
  const int tid = threadIdx.x;
  __shared__ float buf[SFRAMES * 40];
  __shared__ float lsum[256];
  for (int i = tid; i < SFRAMES * OUTC; i += 256) {
    const int s = i / OUTC, o = i - s * OUTC;
    buf[s * 40 + o] = Y[((size_t)s * 32 + b) * OUTC + o];
  }
  __syncthreads();
  if (tid < OUTC) {
    const float ar = 1.0f / (1.0f + expf(-tau_ro[tid]));
    const float omr = 1.0f - ar;
    float m = 0.0f;
#pragma unroll 4
    for (int s = 0; s < SFRAMES; ++s) {
      m = ar * m + omr * buf[s * 40 + tid];
      buf[s * 40 + tid] = m;                  // in-place: buf becomes mems
    }
  }
  __syncthreads();
  float nacc = 0.0f;
  for (int s = tid; s < SFRAMES; s += 256) {
    float mx = -1e30f;
    for (int j = 0; j < OUTC; ++j) mx = fmaxf(mx, buf[s * 40 + j]);
    float se = 0.0f;
    for (int j = 0; j < OUTC; ++j) se += expf(buf[s * 40 + j] - mx);
    const float lse = logf(se);
    float* op = out + ((size_t)s * 32 + b) * OUTC;
    for (int j = 0; j < OUTC; ++j) op[j] = buf[s * 40 + j] - mx - lse;
    const int lab = labels[b * SFRAMES + s];
    nacc += -(buf[s * 40 + lab] - mx - lse);
  }
  lsum[tid] = nacc;
  __syncthreads();
  for (int off = 128; off > 0; off >>= 1) {
    if (tid < off) lsum[tid] += lsum[tid + off];
    __syncthreads();
  }
  if (tid == 0) atomicAdd(out + SFRAMES * 32 * OUTC, lsum[0] * (1.0f / 32.0f));
}

// -------------------------------------------------------------- launch ----
extern "C" void kernel_launch(void* const* d_in, const int* in_sizes, int n_in,
                              void* d_out, int out_size, void* d_ws, size_t ws_size,
                              hipStream_t stream)
{
  const float* x        = (const float*)d_in[0];
  const int*   labels   = (const int*)d_in[1];
  const float* w_fw     = (const float*)d_in[2];
  const float* b_fw     = (const float*)d_in[3];
  const float* tau_m_fw = (const float*)d_in[4];
  const float* tau_n_fw = (const float*)d_in[5];
  const float* mask_fw  = (const float*)d_in[6];
  const float* w_bw     = (const float*)d_in[7];
  const float* b_bw     = (const float*)d_in[8];
  const float* tau_m_bw = (const float*)d_in[9];
  const float* tau_n_bw = (const float*)d_in[10];
  const float* mask_bw  = (const float*)d_in[11];
  const float* w_ro     = (const float*)d_in[12];
  const float* b_ro     = (const float*)d_in[13];
  const float* tau_m_ro = (const float*)d_in[14];
  float* out = (float*)d_out;

  char* ws = (char*)d_ws;
  float* WiT    = (float*)(ws + WS_WIT);
  float* Wspk   = (float*)(ws + WS_WSPK);
  u16*   OFFspk = (u16*)(ws + WS_OFFSPK);
  float* CBIAS  = (float*)(ws + WS_CBIAS);
  float* BETA   = (float*)(ws + WS_BETA);
  float* ALPHA  = (float*)(ws + WS_ALPHA);
  float* FRAMES = (float*)(ws + WS_FRAMES);
  float* Y      = (float*)(ws + WS_Y);
  u16*   LINH   = (u16*)(ws + WS_LINH);

  hipMemsetAsync(out + SFRAMES * 32 * OUTC, 0, sizeof(float), stream);
  hipMemsetAsync(WiT, 0, 638976u, stream);   // zero dense input-weight table

  build_tables<<<1024, 256, 0, stream>>>(w_fw, b_fw, tau_n_fw, mask_fw,
                                         w_bw, b_bw, tau_n_bw, mask_bw,
                                         tau_m_fw, tau_m_bw,
                                         WiT, Wspk, OFFspk, CBIAS, BETA, ALPHA);
  lin_precompute<<<401, 256, 0, stream>>>(x, WiT, CBIAS, LINH);
  snn_scan<<<64, 64, 0, stream>>>(LINH, Wspk, OFFspk, BETA, ALPHA, FRAMES);
  ro_matmul<<<2 * SFRAMES, 256, 0, stream>>>(FRAMES, w_ro, b_ro, Y);
  ro_scan<<<32, 256, 0, stream>>>(Y, tau_m_ro, labels, out);
}

// Round 8
// 390.475 us; speedup vs baseline: 2.7594x; 1.6433x over previous
//
#include <hip/hip_runtime.h>
#include <math.h>

typedef unsigned short u16;
typedef unsigned int u32;
typedef unsigned long long u64;
typedef float v2f __attribute__((ext_vector_type(2)));

#define NSYN 37
#define NB   2048
#define KS   296
#define NIN  39
#define TSTEPS 2000
#define SFRAMES 200
#define HID 256
#define OUTC 39
#define NBLK 204          // LIN blocks alloc'd per chain (fw uses 200, bw 201, pad)

// ws layout (byte offsets, 16B aligned)
#define WS_WIT    0u          // float [2][39][2048] dense input weights (transposed)
#define WS_WSPK   638976u     // float [2][37][2048] spike-synapse weights
#define WS_OFFSPK 1245184u    // u16   [2][37][2048] spike LDS byte offsets
#define WS_CBIAS  1548288u    // float [2][2048]     raw bias
#define WS_BETA   1564672u    // float [2][2048]
#define WS_ALPHA  1581056u    // float [2][256]
#define WS_FRAMES 1583104u    // float [2][32][200][256]
#define WS_Y      14690304u   // float [200][32][39]
#define WS_LINH   15688704u   // u16/fp16 [64 chains][204 blocks][2048] commit-ordered

#define VMW0() asm volatile("s_waitcnt vmcnt(0)" ::: "memory")

// ---------------------------------------------------------------- setup ----
// one WAVE per (dir,row): coalesced mask reads + ballot compaction
__global__ __launch_bounds__(256) void build_tables(
    const float* __restrict__ w_fw, const float* __restrict__ b_fw,
    const float* __restrict__ tau_n_fw, const float* __restrict__ mask_fw,
    const float* __restrict__ w_bw, const float* __restrict__ b_bw,
    const float* __restrict__ tau_n_bw, const float* __restrict__ mask_bw,
    const float* __restrict__ tau_m_fw, const float* __restrict__ tau_m_bw,
    float* __restrict__ WiT, float* __restrict__ Wspk, u16* __restrict__ OFFspk,
    float* __restrict__ CBIAS, float* __restrict__ BETA, float* __restrict__ ALPHA)
{
  const int row = blockIdx.x * 4 + (threadIdx.x >> 6);   // 0..4095
  const int l = threadIdx.x & 63;
  const int dir = row >> 11, r = row & (NB - 1);
  const float* w  = dir ? w_bw : w_fw;
  const float* mk = dir ? mask_bw : mask_fw;
  float* wit = WiT + (size_t)dir * (NIN * NB);
  float* wsp = Wspk + (size_t)dir * (NSYN * NB);
  u16*   osp = OFFspk + (size_t)dir * (NSYN * NB);
  const u64 ltm = (1ull << l) - 1ull;
  int sc = 0;
#pragma unroll
  for (int ch = 0; ch < 5; ++ch) {
    const int j = ch * 64 + l;
    const float m = (j < KS) ? mk[(size_t)r * KS + j] : 0.0f;
    const u64 bits = __ballot(m != 0.0f);
    const u64 sbits = (ch == 0) ? ((bits >> NIN) << NIN) : bits;  // entries j>=39
    if (m != 0.0f) {
      const float wv = w[(size_t)r * KS + j];
      if (j < NIN) {
        wit[(size_t)j * NB + r] = wv;
      } else {
        const int pos = sc + (int)__popcll(sbits & ltm);
        if (pos < NSYN) {
          wsp[(size_t)pos * NB + r] = wv;
          osp[(size_t)pos * NB + r] = (u16)((j - NIN) * 4);
        }
      }
    }
    sc += (int)__popcll(sbits);
  }
  for (int p = sc + l; p < NSYN; p += 64) {   // pad -> permanent-zero slot
    wsp[(size_t)p * NB + r] = 0.0f;
    osp[(size_t)p * NB + r] = (u16)(256 * 4);
  }
  if (l == 0) {
    const float* tn = dir ? tau_n_bw : tau_n_fw;
    const float* bb = dir ? b_bw : b_fw;
    BETA[dir * NB + r]  = 1.0f / (1.0f + expf(-tn[r]));
    CBIAS[dir * NB + r] = bb[r];
    if (r < HID) {
      const float* tm = dir ? tau_m_bw : tau_m_fw;
      ALPHA[dir * HID + r] = 1.0f / (1.0f + expf(-tm[r]));
    }
  }
}

// --------------------------------------------- per-frame input lin (fp16) ----
// LINH[chain][c][2048] in COMMIT order (fw: c->frame c; bw: c0->f0, c>=1 -> f(200-c)),
// chunk-permuted so scan lane l chunk q holds branches l*32+q*8..+7 at (q*64+l)*8.
__global__ __launch_bounds__(256) void lin_precompute(
    const float* __restrict__ x, const float* __restrict__ WiT,
    const float* __restrict__ CBIAS, u16* __restrict__ LINH)
{
  const int bid = blockIdx.x;   // 0..400
  int dir, c, fr;
  if (bid < 200) { dir = 0; c = bid; fr = c; }
  else { dir = 1; c = bid - 200; fr = (c == 0) ? 0 : (200 - c); }
  const int t = threadIdx.x;
  const int r0 = t * 8;
  __shared__ float xs[32 * NIN];
  for (int i = t; i < 32 * NIN; i += 256) {
    const int b = i / NIN, cc = i - b * NIN;
    xs[i] = x[(size_t)b * (SFRAMES * NIN) + fr * NIN + cc];
  }
  __syncthreads();
  const float* wit = WiT + (size_t)dir * (NIN * NB) + r0;
  float bias[8];
  *reinterpret_cast<float4*>(&bias[0]) = *reinterpret_cast<const float4*>(CBIAS + dir * NB + r0);
  *reinterpret_cast<float4*>(&bias[4]) = *reinterpret_cast<const float4*>(CBIAS + dir * NB + r0 + 4);
  const int lpos = ((t & 3) * 64 + (t >> 2)) * 8;   // permuted offset
#pragma unroll 1
  for (int bt = 0; bt < 8; ++bt) {
    float acc[4][8];
#pragma unroll
    for (int q = 0; q < 4; ++q)
#pragma unroll
      for (int k = 0; k < 8; ++k) acc[q][k] = 0.0f;
#pragma unroll 1
    for (int cc = 0; cc < NIN; ++cc) {
      float wv[8];
      *reinterpret_cast<float4*>(&wv[0]) = *reinterpret_cast<const float4*>(wit + cc * NB);
      *reinterpret_cast<float4*>(&wv[4]) = *reinterpret_cast<const float4*>(wit + cc * NB + 4);
#pragma unroll
      for (int q = 0; q < 4; ++q) {
        const float sx = xs[(bt * 4 + q) * NIN + cc];
#pragma unroll
        for (int k = 0; k < 8; ++k) acc[q][k] += wv[k] * sx;
      }
    }
#pragma unroll
    for (int q = 0; q < 4; ++q) {
      const int b = bt * 4 + q;
      u16* dst = LINH + ((size_t)(dir * 32 + b) * NBLK + c) * NB + lpos;
      union { u16 h[8]; uint4 u; } pk;
#pragma unroll
      for (int k = 0; k < 8; ++k) {
        const _Float16 hv = (_Float16)(acc[q][k] + bias[k]);
        pk.h[k] = *reinterpret_cast<const u16*>(&hv);
      }
      *reinterpret_cast<uint4*>(dst) = pk.u;
    }
  }
}

// ------------------------------------------------------- recurrent core ----
__device__ __forceinline__ void gload_lds16(const void* g, void* l) {
  __builtin_amdgcn_global_load_lds(
      (const __attribute__((address_space(1))) void*)g,
      (__attribute__((address_space(3))) void*)l, 16, 0, 0);
}

// grid = 64 chains (dir*32 + b), block = 64 (ONE wave). Lane l owns neurons
// 4l..4l+3 (branches 32l..32l+31), state e = d - lin. Window (frame) structure:
// fast path = 10 straight-line silent steps + one spike-certification __any;
// bitwise-identical to the slow path's silent branch, so no guard band needed.
// Slow path (spikes live / certification failed): restore window-start state,
// re-run the window with per-step gathers+publishes.
__global__ __launch_bounds__(64, 1) void snn_scan(
    const u16* __restrict__ LINH, const float* __restrict__ Wspk,
    const u16* __restrict__ OFFspk, const float* __restrict__ BETA,
    const float* __restrict__ ALPHA, float* __restrict__ FRAMES)
{
  const int chain = blockIdx.x;
  const int dir = chain >> 5;
  const int l = threadIdx.x;

  __shared__ __align__(16) u16 ring[4][NB];   // lin fp16 4-slot ring
  __shared__ __align__(16) float spkbuf[260]; // spikes; slots 256..259 stay 0

  {
    const float4 z4 = {0.f, 0.f, 0.f, 0.f};
    *reinterpret_cast<float4*>(&spkbuf[l * 4]) = z4;
    if (l == 0) *reinterpret_cast<float4*>(&spkbuf[256]) = z4;
    const uint4 zu = {0u, 0u, 0u, 0u};
    uint4* zz = reinterpret_cast<uint4*>(&ring[3][l * 32]);   // lin(-1) = 0
    zz[0] = zu; zz[1] = zu; zz[2] = zu; zz[3] = zu;
  }

  v2f e2[4][4], be2[4][4];
  float Sl[4] = {0.f, 0.f, 0.f, 0.f};
  float mem[4] = {0.f, 0.f, 0.f, 0.f};
  float sp[4] = {0.f, 0.f, 0.f, 0.f};
  float al[4], om[4];
#pragma unroll
  for (int q = 0; q < 4; ++q) {
    const v2f* bp = reinterpret_cast<const v2f*>(BETA + dir * NB + l * 32 + q * 8);
#pragma unroll
    for (int i = 0; i < 4; ++i) { be2[q][i] = bp[i]; e2[q][i] = (v2f){0.f, 0.f}; }
    al[q] = ALPHA[dir * HID + l * 4 + q];
    om[q] = 1.0f - al[q];
  }

  const u16* LB = LINH + (size_t)chain * NBLK * NB;
#pragma unroll
  for (int i = 0; i < 4; ++i) {
    gload_lds16(LB + 0 * NB + i * 512 + l * 8, &ring[0][i * 512]);
    gload_lds16(LB + 1 * NB + i * 512 + l * 8, &ring[1][i * 512]);
  }

  const float* wsp = Wspk + (size_t)dir * (NSYN * NB) + l * 32;
  const u16*  ofp = OFFspk + (size_t)dir * (NSYN * NB) + l * 32;
  float* frow = FRAMES + (size_t)chain * (SFRAMES * HID) + l * 4;

  int F = 0, c = 0;
  float mmax[4], facc[4];
  float4 pend = {0.f, 0.f, 0.f, 0.f};

  auto tree8 = [](const v2f v[4]) -> float {
    const v2f a = v[0] + v[1];
    const v2f b = v[2] + v[3];
    const v2f t = a + b;
    return t.x + t.y;
  };

  auto commit = [&](bool dopref) {
    const int sn = c & 3, so = (c + 3) & 3;
#pragma unroll
    for (int q = 0; q < 4; ++q) {
      const uint4 vn = *reinterpret_cast<const uint4*>(&ring[sn][(q * 64 + l) * 8]);
      const uint4 vo = *reinterpret_cast<const uint4*>(&ring[so][(q * 64 + l) * 8]);
      const _Float16* hn = reinterpret_cast<const _Float16*>(&vn);
      const _Float16* ho = reinterpret_cast<const _Float16*>(&vo);
      v2f ln2[4];
#pragma unroll
      for (int i = 0; i < 4; ++i) {
        const float fn0 = (float)hn[2 * i], fn1 = (float)hn[2 * i + 1];
        v2f dd; dd.x = (float)ho[2 * i] - fn0; dd.y = (float)ho[2 * i + 1] - fn1;
        e2[q][i] += dd;
        ln2[i].x = fn0; ln2[i].y = fn1;
      }
      Sl[q] = tree8(ln2);
    }
    if (dopref) {                       // prefetch 2 blocks ahead; slot disjoint
      const u16* src = LB + (size_t)(c + 2) * NB;
      u16* dst = &ring[(c + 2) & 3][0];
#pragma unroll
      for (int i = 0; i < 4; ++i)
        gload_lds16(src + i * 512 + l * 8, dst + i * 512);
    }
    ++c;
  };

  auto fstep = [&]() {
#pragma unroll
    for (int q = 0; q < 4; ++q)
#pragma unroll
      for (int i = 0; i < 4; ++i) e2[q][i] *= be2[q][i];
#pragma unroll
    for (int q = 0; q < 4; ++q) {
      const float esum = tree8(e2[q]);
      const float dsum = esum + Sl[q];
      mem[q] = fmaf(al[q], mem[q], fmaf(om[q], dsum, -sp[q]));
      mmax[q] = fmaxf(mmax[q], mem[q]);
    }
  };

  auto sstep = [&]() {
    if (__builtin_expect(F, 0)) {       // spikes live: exact gather
      float scv[4][8];
#pragma unroll
      for (int q = 0; q < 4; ++q)
#pragma unroll
        for (int j = 0; j < 8; ++j) scv[q][j] = 0.0f;
      const char* kb = reinterpret_cast<const char*>(&spkbuf[0]);
#pragma unroll 1
      for (int s = 0; s < NSYN; ++s) {
#pragma unroll
        for (int q = 0; q < 4; ++q) {
          float wv[8];
          *reinterpret_cast<float4*>(&wv[0]) =
              *reinterpret_cast<const float4*>(wsp + (size_t)s * NB + q * 8);
          *reinterpret_cast<float4*>(&wv[4]) =
              *reinterpret_cast<const float4*>(wsp + (size_t)s * NB + q * 8 + 4);
          const uint4 ov = *reinterpret_cast<const uint4*>(ofp + (size_t)s * NB + q * 8);
          const u16* of = reinterpret_cast<const u16*>(&ov);
#pragma unroll
          for (int j = 0; j < 8; ++j)
            scv[q][j] += wv[j] * *reinterpret_cast<const float*>(kb + of[j]);
        }
      }
#pragma unroll
      for (int q = 0; q < 4; ++q)
#pragma unroll
        for (int i = 0; i < 4; ++i) {
          v2f sc2; sc2.x = scv[q][2 * i]; sc2.y = scv[q][2 * i + 1];
          const v2f one = {1.0f, 1.0f};
          e2[q][i] = be2[q][i] * e2[q][i] + (one - be2[q][i]) * sc2;
        }
    } else {                            // silent: identical to fstep core
#pragma unroll
      for (int q = 0; q < 4; ++q)
#pragma unroll
        for (int i = 0; i < 4; ++i) e2[q][i] *= be2[q][i];
    }
    float ssum = 0.0f;
#pragma unroll
    for (int q = 0; q < 4; ++q) {
      const float esum = tree8(e2[q]);
      const float dsum = esum + Sl[q];
      mem[q] = fmaf(al[q], mem[q], fmaf(om[q], dsum, -sp[q]));
      sp[q] = (mem[q] > 1.0f) ? 1.0f : 0.0f;
      facc[q] += sp[q];
      ssum += sp[q];
    }
    const float4 sv = {sp[0], sp[1], sp[2], sp[3]};
    *reinterpret_cast<float4*>(&spkbuf[l * 4]) = sv;
    F = __any(ssum > 0.0f);
  };

#pragma unroll 1
  for (int w = 0; w < SFRAMES; ++w) {
    // save window-start state for possible slow redo
    v2f es[4][4]; float Sls[4], mems_[4], sps[4];
#pragma unroll
    for (int q = 0; q < 4; ++q) {
#pragma unroll
      for (int i = 0; i < 4; ++i) es[q][i] = e2[q][i];
      Sls[q] = Sl[q]; mems_[q] = mem[q]; sps[q] = sp[q];
    }
    const int cs = c;
    bool slow = (F != 0);
    bool prefed = false;

    if (!slow) {
      prefed = true;
      mmax[0] = mmax[1] = mmax[2] = mmax[3] = -1e30f;
      if (dir == 0) {
        VMW0(); commit(true);
        if (w) *reinterpret_cast<float4*>(frow + (w - 1) * HID) = pend;
#pragma unroll
        for (int t = 0; t < 10; ++t) fstep();
      } else {
        if (w == 0) { VMW0(); commit(true); }
        fstep();
        VMW0(); commit(true);
        if (w) *reinterpret_cast<float4*>(frow + (w - 1) * HID) = pend;
#pragma unroll
        for (int t = 0; t < 9; ++t) fstep();
      }
      const int viol = (mmax[0] > 1.0f) || (mmax[1] > 1.0f) ||
                       (mmax[2] > 1.0f) || (mmax[3] > 1.0f);
      slow = (__any(viol) != 0);
      if (!slow) {
        pend = (float4){0.f, 0.f, 0.f, 0.f};   // facc = 0 exactly
      } else {                                  // restore + redo
#pragma unroll
        for (int q = 0; q < 4; ++q) {
#pragma unroll
          for (int i = 0; i < 4; ++i) e2[q][i] = es[q][i];
          Sl[q] = Sls[q]; mem[q] = mems_[q]; sp[q] = sps[q];
        }
        c = cs;
      }
    }
    if (slow) {
      facc[0] = facc[1] = facc[2] = facc[3] = 0.0f;
      if (dir == 0) {
        VMW0(); commit(!prefed);
        if (w) *reinterpret_cast<float4*>(frow + (w - 1) * HID) = pend;
#pragma unroll 1
        for (int t = 0; t < 10; ++t) sstep();
      } else {
        if (w == 0) { VMW0(); commit(!prefed); }
        sstep();
        VMW0(); commit(!prefed);
        if (w) *reinterpret_cast<float4*>(frow + (w - 1) * HID) = pend;
#pragma unroll 1
        for (int t = 0; t < 9; ++t) sstep();
      }
      pend = (float4){facc[0] * 0.1f, facc[1] * 0.1f, facc[2] * 0.1f, facc[3] * 0.1f};
    }
  }
  *reinterpret_cast<float4*>(frow + (SFRAMES - 1) * HID) = pend;
}

// ------------------------------------------------------------- readout ----
// grid = 400 (s, half): per block 16 batch-rows x 39 outs, K=512 in 4 chunks
// of 128, both operands LDS-staged with coalesced loads; vectorized b128 dots.
__global__ __launch_bounds__(256) void ro_matmul(
    const float* __restrict__ FRAMES, const float* __restrict__ w_ro,
    const float* __restrict__ b_ro, float* __restrict__ Y)
{
  const int bid = blockIdx.x;
  const int s = bid >> 1, b0 = (bid & 1) * 16;
  __shared__ float rowc[16 * 132];    // stride 132: 16B-aligned, banks bb*4
  __shared__ float wlds[48 * 132];    // rows 39..47 read-but-guarded garbage
  const int bb = threadIdx.x >> 4;
  const int oc = threadIdx.x & 15;
  const int o1 = oc + 16, o2 = oc + 32;
  float a0 = 0.f, a1 = 0.f, a2 = 0.f;
  const bool u2 = (o2 < OUTC);

#pragma unroll 1
  for (int kc = 0; kc < 4; ++kc) {
    // stage 16 FRAMES sub-rows (fw chunks 0,1; bw chunks 2,3), coalesced
    for (int i = threadIdx.x; i < 16 * 128; i += 256) {
      const int rb = i >> 7, kk = i & 127;
      float v;
      if (kc < 2)
        v = FRAMES[((size_t)(b0 + rb) * SFRAMES + s) * HID + kc * 128 + kk];
      else
        v = FRAMES[((size_t)(32 + b0 + rb) * SFRAMES + (199 - s)) * HID + (kc - 2) * 128 + kk];
      rowc[rb * 132 + kk] = v;
    }
    // stage w_ro k-slice, coalesced
    for (int i = threadIdx.x; i < OUTC * 128; i += 256) {
      const int o = i >> 7, kk = i & 127;
      wlds[o * 132 + kk] = w_ro[(size_t)o * 512 + kc * 128 + kk];
    }
    __syncthreads();

    const float* rp = &rowc[bb * 132];
    const float* w0 = &wlds[oc * 132];
    const float* w1 = &wlds[o1 * 132];
    const float* w2 = &wlds[o2 * 132];
#pragma unroll 8
    for (int kk = 0; kk < 128; kk += 4) {
      const float4 a  = *reinterpret_cast<const float4*>(rp + kk);
      const float4 v0 = *reinterpret_cast<const float4*>(w0 + kk);
      const float4 v1 = *reinterpret_cast<const float4*>(w1 + kk);
      const float4 v2 = *reinterpret_cast<const float4*>(w2 + kk);
      a0 = fmaf(a.x, v0.x, fmaf(a.y, v0.y, fmaf(a.z, v0.z, fmaf(a.w, v0.w, a0))));
      a1 = fmaf(a.x, v1.x, fmaf(a.y, v1.y, fmaf(a.z, v1.z, fmaf(a.w, v1.w, a1))));
      if (u2)
        a2 = fmaf(a.x, v2.x, fmaf(a.y, v2.y, fmaf(a.z, v2.z, fmaf(a.w, v2.w, a2))));
    }
    __syncthreads();
  }

  float* yp = Y + ((size_t)s * 32 + b0 + bb) * OUTC;
  yp[oc] = a0 + b_ro[oc];
  yp[o1] = a1 + b_ro[o1];
  if (u2) yp[o2] = a2 + b_ro[o2];
}

__global__ __launch_bounds__(256) void ro_scan(
    const float* __restrict__ Y, const float* __restrict__ tau_ro,
    const int* __restrict__ labels, float* __restrict__ out)
{
  const int b = blockIdx.x;
  const int tid = threadIdx.x;
  __shared__ float buf[SFRAMES * 40];
  __shared__ float lsum[256];
  for (int i = tid; i < SFRAMES * OUTC; i += 256) {
    const int s = i / OUTC, o = i - s * OUTC;
    buf[s * 40 + o] = Y[((size_t)s * 32 + b) * OUTC + o];
  }
  __syncthreads();
  if (tid < OUTC) {
    const float ar = 1.0f / (1.0f + expf(-tau_ro[tid]));
    const float omr = 1.0f - ar;
    float m = 0.0f;
#pragma unroll 4
    for (int s = 0; s < SFRAMES; ++s) {
      m = ar * m + omr * buf[s * 40 + tid];
      buf[s * 40 + tid] = m;                  // in-place: buf becomes mems
    }
  }
  __syncthreads();
  float nacc = 0.0f;
  for (int s = tid; s < SFRAMES; s += 256) {
    float mx = -1e30f;
    for (int j = 0; j < OUTC; ++j) mx = fmaxf(mx, buf[s * 40 + j]);
    float se = 0.0f;
    for (int j = 0; j < OUTC; ++j) se += expf(buf[s * 40 + j] - mx);
    const float lse = logf(se);
    float* op = out + ((size_t)s * 32 + b) * OUTC;
    for (int j = 0; j < OUTC; ++j) op[j] = buf[s * 40 + j] - mx - lse;
    const int lab = labels[b * SFRAMES + s];
    nacc += -(buf[s * 40 + lab] - mx - lse);
  }
  lsum[tid] = nacc;
  __syncthreads();
  for (int off = 128; off > 0; off >>= 1) {
    if (tid < off) lsum[tid] += lsum[tid + off];
    __syncthreads();
  }
  if (tid == 0) atomicAdd(out + SFRAMES * 32 * OUTC, lsum[0] * (1.0f / 32.0f));
}

// -------------------------------------------------------------- launch ----
extern "C" void kernel_launch(void* const* d_in, const int* in_sizes, int n_in,
                              void* d_out, int out_size, void* d_ws, size_t ws_size,
                              hipStream_t stream)
{
  const float* x        = (const float*)d_in[0];
  const int*   labels   = (const int*)d_in[1];
  const float* w_fw     = (const float*)d_in[2];
  const float* b_fw     = (const float*)d_in[3];
  const float* tau_m_fw = (const float*)d_in[4];
  const float* tau_n_fw = (const float*)d_in[5];
  const float* mask_fw  = (const float*)d_in[6];
  const float* w_bw     = (const float*)d_in[7];
  const float* b_bw     = (const float*)d_in[8];
  const float* tau_m_bw = (const float*)d_in[9];
  const float* tau_n_bw = (const float*)d_in[10];
  const float* mask_bw  = (const float*)d_in[11];
  const float* w_ro     = (const float*)d_in[12];
  const float* b_ro     = (const float*)d_in[13];
  const float* tau_m_ro = (const float*)d_in[14];
  float* out = (float*)d_out;

  char* ws = (char*)d_ws;
  float* WiT    = (float*)(ws + WS_WIT);
  float* Wspk   = (float*)(ws + WS_WSPK);
  u16*   OFFspk = (u16*)(ws + WS_OFFSPK);
  float* CBIAS  = (float*)(ws + WS_CBIAS);
  float* BETA   = (float*)(ws + WS_BETA);
  float* ALPHA  = (float*)(ws + WS_ALPHA);
  float* FRAMES = (float*)(ws + WS_FRAMES);
  float* Y      = (float*)(ws + WS_Y);
  u16*   LINH   = (u16*)(ws + WS_LINH);

  hipMemsetAsync(out + SFRAMES * 32 * OUTC, 0, sizeof(float), stream);
  hipMemsetAsync(WiT, 0, 638976u, stream);   // zero dense input-weight table

  build_tables<<<1024, 256, 0, stream>>>(w_fw, b_fw, tau_n_fw, mask_fw,
                                         w_bw, b_bw, tau_n_bw, mask_bw,
                                         tau_m_fw, tau_m_bw,
                                         WiT, Wspk, OFFspk, CBIAS, BETA, ALPHA);
  lin_precompute<<<401, 256, 0, stream>>>(x, WiT, CBIAS, LINH);
  snn_scan<<<64, 64, 0, stream>>>(LINH, Wspk, OFFspk, BETA, ALPHA, FRAMES);
  ro_matmul<<<2 * SFRAMES, 256, 0, stream>>>(FRAMES, w_ro, b_ro, Y);
  ro_scan<<<32, 256, 0, stream>>>(Y, tau_m_ro, labels, out);
}

// Round 9
// 195.664 us; speedup vs baseline: 5.5068x; 1.9956x over previous
//
#include <hip/hip_runtime.h>
#include <math.h>

typedef unsigned short u16;
typedef unsigned int u32;
typedef unsigned long long u64;
typedef float v2f __attribute__((ext_vector_type(2)));

#define NSYN 37
#define NB   2048
#define KS   296
#define NIN  39
#define TSTEPS 2000
#define SFRAMES 200
#define HID 256
#define OUTC 39
#define NBLK 204          // LIN blocks alloc'd per chain (fw uses 200, bw 201, pad)

// ws layout (byte offsets, 16B aligned)
#define WS_WIT    0u          // float [2][39][2048] dense input weights (transposed)
#define WS_WSPK   638976u     // float [2][37][2048] spike-synapse weights
#define WS_OFFSPK 1245184u    // u16   [2][37][2048] spike LDS byte offsets
#define WS_CBIAS  1548288u    // float [2][2048]     raw bias
#define WS_BETA   1564672u    // float [2][2048]
#define WS_ALPHA  1581056u    // float [2][256]
#define WS_FRAMES 1583104u    // float [2][32][200][256]
#define WS_Y      14690304u   // float [200][32][39]
#define WS_LINH   15688704u   // u16/fp16 [64 chains][204 blocks][2048] commit-ordered
#define WS_FLAG   69166080u   // u32: 0 = whole sequence certified silent

#define VMW0() asm volatile("s_waitcnt vmcnt(0)" ::: "memory")

// ---------------------------------------------------------------- setup ----
// one WAVE per (dir,row): coalesced mask reads + ballot compaction
__global__ __launch_bounds__(256) void build_tables(
    const float* __restrict__ w_fw, const float* __restrict__ b_fw,
    const float* __restrict__ tau_n_fw, const float* __restrict__ mask_fw,
    const float* __restrict__ w_bw, const float* __restrict__ b_bw,
    const float* __restrict__ tau_n_bw, const float* __restrict__ mask_bw,
    const float* __restrict__ tau_m_fw, const float* __restrict__ tau_m_bw,
    float* __restrict__ WiT, float* __restrict__ Wspk, u16* __restrict__ OFFspk,
    float* __restrict__ CBIAS, float* __restrict__ BETA, float* __restrict__ ALPHA)
{
  const int row = blockIdx.x * 4 + (threadIdx.x >> 6);   // 0..4095
  const int l = threadIdx.x & 63;
  const int dir = row >> 11, r = row & (NB - 1);
  const float* w  = dir ? w_bw : w_fw;
  const float* mk = dir ? mask_bw : mask_fw;
  float* wit = WiT + (size_t)dir * (NIN * NB);
  float* wsp = Wspk + (size_t)dir * (NSYN * NB);
  u16*   osp = OFFspk + (size_t)dir * (NSYN * NB);
  const u64 ltm = (1ull << l) - 1ull;
  int sc = 0;
#pragma unroll
  for (int ch = 0; ch < 5; ++ch) {
    const int j = ch * 64 + l;
    const float m = (j < KS) ? mk[(size_t)r * KS + j] : 0.0f;
    const u64 bits = __ballot(m != 0.0f);
    const u64 sbits = (ch == 0) ? ((bits >> NIN) << NIN) : bits;  // entries j>=39
    if (m != 0.0f) {
      const float wv = w[(size_t)r * KS + j];
      if (j < NIN) {
        wit[(size_t)j * NB + r] = wv;
      } else {
        const int pos = sc + (int)__popcll(sbits & ltm);
        if (pos < NSYN) {
          wsp[(size_t)pos * NB + r] = wv;
          osp[(size_t)pos * NB + r] = (u16)((j - NIN) * 4);
        }
      }
    }
    sc += (int)__popcll(sbits);
  }
  for (int p = sc + l; p < NSYN; p += 64) {   // pad -> permanent-zero slot
    wsp[(size_t)p * NB + r] = 0.0f;
    osp[(size_t)p * NB + r] = (u16)(256 * 4);
  }
  if (l == 0) {
    const float* tn = dir ? tau_n_bw : tau_n_fw;
    const float* bb = dir ? b_bw : b_fw;
    BETA[dir * NB + r]  = 1.0f / (1.0f + expf(-tn[r]));
    CBIAS[dir * NB + r] = bb[r];
    if (r < HID) {
      const float* tm = dir ? tau_m_bw : tau_m_fw;
      ALPHA[dir * HID + r] = 1.0f / (1.0f + expf(-tm[r]));
    }
  }
}

// --------------------------------------------- per-frame input lin (fp16) ----
// LINH[chain][c][2048] in COMMIT order (fw: c->frame c; bw: c0->f0, c>=1 -> f(200-c)),
// chunk-permuted so scan lane l chunk q holds branches l*32+q*8..+7 at (q*64+l)*8.
__global__ __launch_bounds__(256) void lin_precompute(
    const float* __restrict__ x, const float* __restrict__ WiT,
    const float* __restrict__ CBIAS, u16* __restrict__ LINH)
{
  const int bid = blockIdx.x;   // 0..400
  int dir, c, fr;
  if (bid < 200) { dir = 0; c = bid; fr = c; }
  else { dir = 1; c = bid - 200; fr = (c == 0) ? 0 : (200 - c); }
  const int t = threadIdx.x;
  const int r0 = t * 8;
  __shared__ float xs[32 * NIN];
  for (int i = t; i < 32 * NIN; i += 256) {
    const int b = i / NIN, cc = i - b * NIN;
    xs[i] = x[(size_t)b * (SFRAMES * NIN) + fr * NIN + cc];
  }
  __syncthreads();
  const float* wit = WiT + (size_t)dir * (NIN * NB) + r0;
  float bias[8];
  *reinterpret_cast<float4*>(&bias[0]) = *reinterpret_cast<const float4*>(CBIAS + dir * NB + r0);
  *reinterpret_cast<float4*>(&bias[4]) = *reinterpret_cast<const float4*>(CBIAS + dir * NB + r0 + 4);
  const int lpos = ((t & 3) * 64 + (t >> 2)) * 8;   // permuted offset
#pragma unroll 1
  for (int bt = 0; bt < 8; ++bt) {
    float acc[4][8];
#pragma unroll
    for (int q = 0; q < 4; ++q)
#pragma unroll
      for (int k = 0; k < 8; ++k) acc[q][k] = 0.0f;
#pragma unroll 1
    for (int cc = 0; cc < NIN; ++cc) {
      float wv[8];
      *reinterpret_cast<float4*>(&wv[0]) = *reinterpret_cast<const float4*>(wit + cc * NB);
      *reinterpret_cast<float4*>(&wv[4]) = *reinterpret_cast<const float4*>(wit + cc * NB + 4);
#pragma unroll
      for (int q = 0; q < 4; ++q) {
        const float sx = xs[(bt * 4 + q) * NIN + cc];
#pragma unroll
        for (int k = 0; k < 8; ++k) acc[q][k] += wv[k] * sx;
      }
    }
#pragma unroll
    for (int q = 0; q < 4; ++q) {
      const int b = bt * 4 + q;
      u16* dst = LINH + ((size_t)(dir * 32 + b) * NBLK + c) * NB + lpos;
      union { u16 h[8]; uint4 u; } pk;
#pragma unroll
      for (int k = 0; k < 8; ++k) {
        const _Float16 hv = (_Float16)(acc[q][k] + bias[k]);
        pk.h[k] = *reinterpret_cast<const u16*>(&hv);
      }
      *reinterpret_cast<uint4*>(dst) = pk.u;
    }
  }
}

// -------------------------------------------- parallel silent certificate ----
// One thread per (chain, neuron): replays the serial scan's fast-path math
// BITWISE (same fp16 inputs, same expression trees) for all 2000 steps and
// flags if any window would spike. flag==0 => serial scan provably all-fast,
// all spikes zero, FRAMES == 0.
__global__ __launch_bounds__(256) void cert_scan(
    const u16* __restrict__ LINH, const float* __restrict__ BETA,
    const float* __restrict__ ALPHA, u32* __restrict__ flag)
{
  const int chain = blockIdx.x;
  const int dir = chain >> 5;
  const int tid = threadIdx.x;          // == q*64 + l  (matches LINH layout)
  const int l = tid & 63, q = tid >> 6;

  v2f e2[4], be2[4];
  const v2f* bp = reinterpret_cast<const v2f*>(BETA + dir * NB + l * 32 + q * 8);
#pragma unroll
  for (int i = 0; i < 4; ++i) { be2[i] = bp[i]; e2[i] = (v2f){0.f, 0.f}; }
  const float al = ALPHA[dir * HID + l * 4 + q];
  const float om = 1.0f - al;
  const float sp = 0.0f;

  float Sl = 0.0f, mem = 0.0f, mmax = -1e30f;
  uint4 lino = {0u, 0u, 0u, 0u};
  bool fail = false;

  const u16* LB = LINH + (size_t)chain * NBLK * NB;
  auto ld = [&](int c) {
    return *reinterpret_cast<const uint4*>(LB + (size_t)c * NB + tid * 8);
  };
  auto tree8 = [](const v2f v[4]) -> float {
    const v2f a = v[0] + v[1];
    const v2f b = v[2] + v[3];
    const v2f t = a + b;
    return t.x + t.y;
  };
  auto commit = [&](uint4 vn) {
    const _Float16* hn = reinterpret_cast<const _Float16*>(&vn);
    const _Float16* ho = reinterpret_cast<const _Float16*>(&lino);
    v2f ln2[4];
#pragma unroll
    for (int i = 0; i < 4; ++i) {
      const float fn0 = (float)hn[2 * i], fn1 = (float)hn[2 * i + 1];
      v2f dd; dd.x = (float)ho[2 * i] - fn0; dd.y = (float)ho[2 * i + 1] - fn1;
      e2[i] += dd;
      ln2[i].x = fn0; ln2[i].y = fn1;
    }
    Sl = tree8(ln2);
    lino = vn;
  };
  auto fstep = [&]() {
#pragma unroll
    for (int i = 0; i < 4; ++i) e2[i] *= be2[i];
    const float esum = tree8(e2);
    const float dsum = esum + Sl;
    mem = fmaf(al, mem, fmaf(om, dsum, -sp));
    mmax = fmaxf(mmax, mem);
  };

  uint4 p0 = ld(0), p1 = ld(1);

  if (dir == 0) {
#pragma unroll 1
    for (int w = 0; w < SFRAMES; w += 2) {
      mmax = -1e30f;
      commit(p0); p0 = ld(w + 2);
#pragma unroll
      for (int t = 0; t < 10; ++t) fstep();
      fail = fail || (mmax > 1.0f);
      mmax = -1e30f;
      commit(p1); p1 = ld(w + 3);
#pragma unroll
      for (int t = 0; t < 10; ++t) fstep();
      fail = fail || (mmax > 1.0f);
    }
  } else {
    // window 0: commit b0; 1 step; commit b1; 9 steps
    mmax = -1e30f;
    commit(p0); p0 = ld(2);
    fstep();
    commit(p1); p1 = ld(3);
#pragma unroll
    for (int t = 0; t < 9; ++t) fstep();
    fail = fail || (mmax > 1.0f);
    // windows 1..198 in pairs: {1 step old; commit b(w+1); 9 steps}
#pragma unroll 1
    for (int w = 1; w < 199; w += 2) {
      mmax = -1e30f;
      fstep();
      commit(p0); p0 = ld(w + 3);
#pragma unroll
      for (int t = 0; t < 9; ++t) fstep();
      fail = fail || (mmax > 1.0f);
      mmax = -1e30f;
      fstep();
      commit(p1); p1 = ld(w + 4);
#pragma unroll
      for (int t = 0; t < 9; ++t) fstep();
      fail = fail || (mmax > 1.0f);
    }
    // window 199: 1 step; commit b200 (parity 0); 9 steps
    mmax = -1e30f;
    fstep();
    commit(p0);
#pragma unroll
    for (int t = 0; t < 9; ++t) fstep();
    fail = fail || (mmax > 1.0f);
  }

  if (__any(fail ? 1 : 0) && (tid & 63) == 0) atomicOr(flag, 1u);
}

// ------------------------------------------------------- recurrent core ----
__device__ __forceinline__ void gload_lds16(const void* g, void* l) {
  __builtin_amdgcn_global_load_lds(
      (const __attribute__((address_space(1))) void*)g,
      (__attribute__((address_space(3))) void*)l, 16, 0, 0);
}

// grid = 64 chains (dir*32 + b), block = 64 (ONE wave). Early-exits when the
// cert kernel proved the whole sequence silent (FRAMES pre-zeroed by memset).
__global__ __launch_bounds__(64, 1) void snn_scan(
    const u16* __restrict__ LINH, const float* __restrict__ Wspk,
    const u16* __restrict__ OFFspk, const float* __restrict__ BETA,
    const float* __restrict__ ALPHA, float* __restrict__ FRAMES,
    const u32* __restrict__ flag)
{
  if (*flag == 0u) return;     // certified silent: FRAMES==0 already correct

  const int chain = blockIdx.x;
  const int dir = chain >> 5;
  const int l = threadIdx.x;

  __shared__ __align__(16) u16 ring[4][NB];   // lin fp16 4-slot ring
  __shared__ __align__(16) float spkbuf[260]; // spikes; slots 256..259 stay 0

  {
    const float4 z4 = {0.f, 0.f, 0.f, 0.f};
    *reinterpret_cast<float4*>(&spkbuf[l * 4]) = z4;
    if (l == 0) *reinterpret_cast<float4*>(&spkbuf[256]) = z4;
    const uint4 zu = {0u, 0u, 0u, 0u};
    uint4* zz = reinterpret_cast<uint4*>(&ring[3][l * 32]);   // lin(-1) = 0
    zz[0] = zu; zz[1] = zu; zz[2] = zu; zz[3] = zu;
  }

  v2f e2[4][4], be2[4][4];
  float Sl[4] = {0.f, 0.f, 0.f, 0.f};
  float mem[4] = {0.f, 0.f, 0.f, 0.f};
  float sp[4] = {0.f, 0.f, 0.f, 0.f};
  float al[4], om[4];
#pragma unroll
  for (int q = 0; q < 4; ++q) {
    const v2f* bp = reinterpret_cast<const v2f*>(BETA + dir * NB + l * 32 + q * 8);
#pragma unroll
    for (int i = 0; i < 4; ++i) { be2[q][i] = bp[i]; e2[q][i] = (v2f){0.f, 0.f}; }
    al[q] = ALPHA[dir * HID + l * 4 + q];
    om[q] = 1.0f - al[q];
  }

  const u16* LB = LINH + (size_t)chain * NBLK * NB;
#pragma unroll
  for (int i = 0; i < 4; ++i) {
    gload_lds16(LB + 0 * NB + i * 512 + l * 8, &ring[0][i * 512]);
    gload_lds16(LB + 1 * NB + i * 512 + l * 8, &ring[1][i * 512]);
  }

  const float* wsp = Wspk + (size_t)dir * (NSYN * NB) + l * 32;
  const u16*  ofp = OFFspk + (size_t)dir * (NSYN * NB) + l * 32;
  float* frow = FRAMES + (size_t)chain * (SFRAMES * HID) + l * 4;

  int F = 0, c = 0;
  float mmax[4], facc[4];
  float4 pend = {0.f, 0.f, 0.f, 0.f};

  auto tree8 = [](const v2f v[4]) -> float {
    const v2f a = v[0] + v[1];
    const v2f b = v[2] + v[3];
    const v2f t = a + b;
    return t.x + t.y;
  };

  auto commit = [&](bool dopref) {
    const int sn = c & 3, so = (c + 3) & 3;
#pragma unroll
    for (int q = 0; q < 4; ++q) {
      const uint4 vn = *reinterpret_cast<const uint4*>(&ring[sn][(q * 64 + l) * 8]);
      const uint4 vo = *reinterpret_cast<const uint4*>(&ring[so][(q * 64 + l) * 8]);
      const _Float16* hn = reinterpret_cast<const _Float16*>(&vn);
      const _Float16* ho = reinterpret_cast<const _Float16*>(&vo);
      v2f ln2[4];
#pragma unroll
      for (int i = 0; i < 4; ++i) {
        const float fn0 = (float)hn[2 * i], fn1 = (float)hn[2 * i + 1];
        v2f dd; dd.x = (float)ho[2 * i] - fn0; dd.y = (float)ho[2 * i + 1] - fn1;
        e2[q][i] += dd;
        ln2[i].x = fn0; ln2[i].y = fn1;
      }
      Sl[q] = tree8(ln2);
    }
    if (dopref) {                       // prefetch 2 blocks ahead; slot disjoint
      const u16* src = LB + (size_t)(c + 2) * NB;
      u16* dst = &ring[(c + 2) & 3][0];
#pragma unroll
      for (int i = 0; i < 4; ++i)
        gload_lds16(src + i * 512 + l * 8, dst + i * 512);
    }
    ++c;
  };

  auto fstep = [&]() {
#pragma unroll
    for (int q = 0; q < 4; ++q)
#pragma unroll
      for (int i = 0; i < 4; ++i) e2[q][i] *= be2[q][i];
#pragma unroll
    for (int q = 0; q < 4; ++q) {
      const float esum = tree8(e2[q]);
      const float dsum = esum + Sl[q];
      mem[q] = fmaf(al[q], mem[q], fmaf(om[q], dsum, -sp[q]));
      mmax[q] = fmaxf(mmax[q], mem[q]);
    }
  };

  auto sstep = [&]() {
    if (__builtin_expect(F, 0)) {       // spikes live: exact gather
      float scv[4][8];
#pragma unroll
      for (int q = 0; q < 4; ++q)
#pragma unroll
        for (int j = 0; j < 8; ++j) scv[q][j] = 0.0f;
      const char* kb = reinterpret_cast<const char*>(&spkbuf[0]);
#pragma unroll 1
      for (int s = 0; s < NSYN; ++s) {
#pragma unroll
        for (int q = 0; q < 4; ++q) {
          float wv[8];
          *reinterpret_cast<float4*>(&wv[0]) =
              *reinterpret_cast<const float4*>(wsp + (size_t)s * NB + q * 8);
          *reinterpret_cast<float4*>(&wv[4]) =
              *reinterpret_cast<const float4*>(wsp + (size_t)s * NB + q * 8 + 4);
          const uint4 ov = *reinterpret_cast<const uint4*>(ofp + (size_t)s * NB + q * 8);
          const u16* of = reinterpret_cast<const u16*>(&ov);
#pragma unroll
          for (int j = 0; j < 8; ++j)
            scv[q][j] += wv[j] * *reinterpret_cast<const float*>(kb + of[j]);
        }
      }
#pragma unroll
      for (int q = 0; q < 4; ++q)
#pragma unroll
        for (int i = 0; i < 4; ++i) {
          v2f sc2; sc2.x = scv[q][2 * i]; sc2.y = scv[q][2 * i + 1];
          const v2f one = {1.0f, 1.0f};
          e2[q][i] = be2[q][i] * e2[q][i] + (one - be2[q][i]) * sc2;
        }
    } else {                            // silent: identical to fstep core
#pragma unroll
      for (int q = 0; q < 4; ++q)
#pragma unroll
        for (int i = 0; i < 4; ++i) e2[q][i] *= be2[q][i];
    }
    float ssum = 0.0f;
#pragma unroll
    for (int q = 0; q < 4; ++q) {
      const float esum = tree8(e2[q]);
      const float dsum = esum + Sl[q];
      mem[q] = fmaf(al[q], mem[q], fmaf(om[q], dsum, -sp[q]));
      sp[q] = (mem[q] > 1.0f) ? 1.0f : 0.0f;
      facc[q] += sp[q];
      ssum += sp[q];
    }
    const float4 sv = {sp[0], sp[1], sp[2], sp[3]};
    *reinterpret_cast<float4*>(&spkbuf[l * 4]) = sv;
    F = __any(ssum > 0.0f);
  };

#pragma unroll 1
  for (int w = 0; w < SFRAMES; ++w) {
    // save window-start state for possible slow redo
    v2f es[4][4]; float Sls[4], mems_[4], sps[4];
#pragma unroll
    for (int q = 0; q < 4; ++q) {
#pragma unroll
      for (int i = 0; i < 4; ++i) es[q][i] = e2[q][i];
      Sls[q] = Sl[q]; mems_[q] = mem[q]; sps[q] = sp[q];
    }
    const int cs = c;
    bool slow = (F != 0);
    bool prefed = false;

    if (!slow) {
      prefed = true;
      mmax[0] = mmax[1] = mmax[2] = mmax[3] = -1e30f;
      if (dir == 0) {
        VMW0(); commit(true);
        if (w) *reinterpret_cast<float4*>(frow + (w - 1) * HID) = pend;
#pragma unroll
        for (int t = 0; t < 10; ++t) fstep();
      } else {
        if (w == 0) { VMW0(); commit(true); }
        fstep();
        VMW0(); commit(true);
        if (w) *reinterpret_cast<float4*>(frow + (w - 1) * HID) = pend;
#pragma unroll
        for (int t = 0; t < 9; ++t) fstep();
      }
      const int viol = (mmax[0] > 1.0f) || (mmax[1] > 1.0f) ||
                       (mmax[2] > 1.0f) || (mmax[3] > 1.0f);
      slow = (__any(viol) != 0);
      if (!slow) {
        pend = (float4){0.f, 0.f, 0.f, 0.f};   // facc = 0 exactly
      } else {                                  // restore + redo
#pragma unroll
        for (int q = 0; q < 4; ++q) {
#pragma unroll
          for (int i = 0; i < 4; ++i) e2[q][i] = es[q][i];
          Sl[q] = Sls[q]; mem[q] = mems_[q]; sp[q] = sps[q];
        }
        c = cs;
      }
    }
    if (slow) {
      facc[0] = facc[1] = facc[2] = facc[3] = 0.0f;
      if (dir == 0) {
        VMW0(); commit(!prefed);
        if (w) *reinterpret_cast<float4*>(frow + (w - 1) * HID) = pend;
#pragma unroll 1
        for (int t = 0; t < 10; ++t) sstep();
      } else {
        if (w == 0) { VMW0(); commit(!prefed); }
        sstep();
        VMW0(); commit(!prefed);
        if (w) *reinterpret_cast<float4*>(frow + (w - 1) * HID) = pend;
#pragma unroll 1
        for (int t = 0; t < 9; ++t) sstep();
      }
      pend = (float4){facc[0] * 0.1f, facc[1] * 0.1f, facc[2] * 0.1f, facc[3] * 0.1f};
    }
  }
  *reinterpret_cast<float4*>(frow + (SFRAMES - 1) * HID) = pend;
}

// ------------------------------------------------------------- readout ----
__global__ __launch_bounds__(256) void ro_matmul(
    const float* __restrict__ FRAMES, const float* __restrict__ w_ro,
    const float* __restrict__ b_ro, float* __restrict__ Y)
{
  const int bid = blockIdx.x;
  const int s = bid >> 1, b0 = (bid & 1) * 16;
  __shared__ float rowc[16 * 132];
  __shared__ float wlds[48 * 132];
  const int bb = threadIdx.x >> 4;
  const int oc = threadIdx.x & 15;
  const int o1 = oc + 16, o2 = oc + 32;
  float a0 = 0.f, a1 = 0.f, a2 = 0.f;
  const bool u2 = (o2 < OUTC);

#pragma unroll 1
  for (int kc = 0; kc < 4; ++kc) {
    for (int i = threadIdx.x; i < 16 * 128; i += 256) {
      const int rb = i >> 7, kk = i & 127;
      float v;
      if (kc < 2)
        v = FRAMES[((size_t)(b0 + rb) * SFRAMES + s) * HID + kc * 128 + kk];
      else
        v = FRAMES[((size_t)(32 + b0 + rb) * SFRAMES + (199 - s)) * HID + (kc - 2) * 128 + kk];
      rowc[rb * 132 + kk] = v;
    }
    for (int i = threadIdx.x; i < OUTC * 128; i += 256) {
      const int o = i >> 7, kk = i & 127;
      wlds[o * 132 + kk] = w_ro[(size_t)o * 512 + kc * 128 + kk];
    }
    __syncthreads();

    const float* rp = &rowc[bb * 132];
    const float* w0 = &wlds[oc * 132];
    const float* w1 = &wlds[o1 * 132];
    const float* w2 = &wlds[o2 * 132];
#pragma unroll 8
    for (int kk = 0; kk < 128; kk += 4) {
      const float4 a  = *reinterpret_cast<const float4*>(rp + kk);
      const float4 v0 = *reinterpret_cast<const float4*>(w0 + kk);
      const float4 v1 = *reinterpret_cast<const float4*>(w1 + kk);
      const float4 v2 = *reinterpret_cast<const float4*>(w2 + kk);
      a0 = fmaf(a.x, v0.x, fmaf(a.y, v0.y, fmaf(a.z, v0.z, fmaf(a.w, v0.w, a0))));
      a1 = fmaf(a.x, v1.x, fmaf(a.y, v1.y, fmaf(a.z, v1.z, fmaf(a.w, v1.w, a1))));
      if (u2)
        a2 = fmaf(a.x, v2.x, fmaf(a.y, v2.y, fmaf(a.z, v2.z, fmaf(a.w, v2.w, a2))));
    }
    __syncthreads();
  }

  float* yp = Y + ((size_t)s * 32 + b0 + bb) * OUTC;
  yp[oc] = a0 + b_ro[oc];
  yp[o1] = a1 + b_ro[o1];
  if (u2) yp[o2] = a2 + b_ro[o2];
}

__global__ __launch_bounds__(256) void ro_scan(
    const float* __restrict__ Y, const float* __restrict__ tau_ro,
    const int* __restrict__ labels, float* __restrict__ out)
{
  const int b = blockIdx.x;
  const int tid = threadIdx.x;
  __shared__ float buf[SFRAMES * 40];
  __shared__ float lsum[256];
  for (int i = tid; i < SFRAMES * OUTC; i += 256) {
    const int s = i / OUTC, o = i - s * OUTC;
    buf[s * 40 + o] = Y[((size_t)s * 32 + b) * OUTC + o];
  }
  __syncthreads();
  if (tid < OUTC) {
    const float ar = 1.0f / (1.0f + expf(-tau_ro[tid]));
    const float omr = 1.0f - ar;
    float m = 0.0f;
#pragma unroll 4
    for (int s = 0; s < SFRAMES; ++s) {
      m = ar * m + omr * buf[s * 40 + tid];
      buf[s * 40 + tid] = m;
    }
  }
  __syncthreads();
  float nacc = 0.0f;
  for (int s = tid; s < SFRAMES; s += 256) {
    float mx = -1e30f;
    for (int j = 0; j < OUTC; ++j) mx = fmaxf(mx, buf[s * 40 + j]);
    float se = 0.0f;
    for (int j = 0; j < OUTC; ++j) se += expf(buf[s * 40 + j] - mx);
    const float lse = logf(se);
    float* op = out + ((size_t)s * 32 + b) * OUTC;
    for (int j = 0; j < OUTC; ++j) op[j] = buf[s * 40 + j] - mx - lse;
    const int lab = labels[b * SFRAMES + s];
    nacc += -(buf[s * 40 + lab] - mx - lse);
  }
  lsum[tid] = nacc;
  __syncthreads();
  for (int off = 128; off > 0; off >>= 1) {
    if (tid < off) lsum[tid] += lsum[tid + off];
    __syncthreads();
  }
  if (tid == 0) atomicAdd(out + SFRAMES * 32 * OUTC, lsum[0] * (1.0f / 32.0f));
}

// -------------------------------------------------------------- launch ----
extern "C" void kernel_launch(void* const* d_in, const int* in_sizes, int n_in,
                              void* d_out, int out_size, void* d_ws, size_t ws_size,
                              hipStream_t stream)
{
  const float* x        = (const float*)d_in[0];
  const int*   labels   = (const int*)d_in[1];
  const float* w_fw     = (const float*)d_in[2];
  const float* b_fw     = (const float*)d_in[3];
  const float* tau_m_fw = (const float*)d_in[4];
  const float* tau_n_fw = (const float*)d_in[5];
  const float* mask_fw  = (const float*)d_in[6];
  const float* w_bw     = (const float*)d_in[7];
  const float* b_bw     = (const float*)d_in[8];
  const float* tau_m_bw = (const float*)d_in[9];
  const float* tau_n_bw = (const float*)d_in[10];
  const float* mask_bw  = (const float*)d_in[11];
  const float* w_ro     = (const float*)d_in[12];
  const float* b_ro     = (const float*)d_in[13];
  const float* tau_m_ro = (const float*)d_in[14];
  float* out = (float*)d_out;

  char* ws = (char*)d_ws;
  float* WiT    = (float*)(ws + WS_WIT);
  float* Wspk   = (float*)(ws + WS_WSPK);
  u16*   OFFspk = (u16*)(ws + WS_OFFSPK);
  float* CBIAS  = (float*)(ws + WS_CBIAS);
  float* BETA   = (float*)(ws + WS_BETA);
  float* ALPHA  = (float*)(ws + WS_ALPHA);
  float* FRAMES = (float*)(ws + WS_FRAMES);
  float* Y      = (float*)(ws + WS_Y);
  u16*   LINH   = (u16*)(ws + WS_LINH);
  u32*   FLAG   = (u32*)(ws + WS_FLAG);

  hipMemsetAsync(out + SFRAMES * 32 * OUTC, 0, sizeof(float), stream);
  hipMemsetAsync(WiT, 0, 638976u, stream);           // zero dense input weights
  hipMemsetAsync(FLAG, 0, sizeof(u32), stream);      // 0 = silent until proven
  hipMemsetAsync(FRAMES, 0, 13107200u, stream);      // correct output if silent

  build_tables<<<1024, 256, 0, stream>>>(w_fw, b_fw, tau_n_fw, mask_fw,
                                         w_bw, b_bw, tau_n_bw, mask_bw,
                                         tau_m_fw, tau_m_bw,
                                         WiT, Wspk, OFFspk, CBIAS, BETA, ALPHA);
  lin_precompute<<<401, 256, 0, stream>>>(x, WiT, CBIAS, LINH);
  cert_scan<<<64, 256, 0, stream>>>(LINH, BETA, ALPHA, FLAG);
  snn_scan<<<64, 64, 0, stream>>>(LINH, Wspk, OFFspk, BETA, ALPHA, FRAMES, FLAG);
  ro_matmul<<<2 * SFRAMES, 256, 0, stream>>>(FRAMES, w_ro, b_ro, Y);
  ro_scan<<<32, 256, 0, stream>>>(Y, tau_m_ro, labels, out);
}

// Round 10
// 184.601 us; speedup vs baseline: 5.8369x; 1.0599x over previous
//
#include <hip/hip_runtime.h>
#include <math.h>

typedef unsigned short u16;
typedef unsigned int u32;
typedef unsigned long long u64;
typedef float v2f __attribute__((ext_vector_type(2)));

#define NSYN 37
#define NB   2048
#define KS   296
#define NIN  39
#define TSTEPS 2000
#define SFRAMES 200
#define HID 256
#define OUTC 39
#define NBLK 204          // LIN blocks alloc'd per chain (fw uses 200, bw 201, pad)

// ws layout (byte offsets, 16B aligned)
#define WS_WIT    0u          // float [2][39][2048] dense input weights (transposed)
#define WS_WSPK   638976u     // float [2][37][2048] spike-synapse weights
#define WS_OFFSPK 1245184u    // u16   [2][37][2048] spike LDS byte offsets
#define WS_CBIAS  1548288u    // float [2][2048]     raw bias
#define WS_BETA   1564672u    // float [2][2048]
#define WS_ALPHA  1581056u    // float [2][256]
#define WS_FRAMES 1583104u    // float [2][32][200][256]
#define WS_Y      14690304u   // float [200][32][39]
#define WS_LINH   15688704u   // u16/fp16 [64 chains][204 blocks][2048] commit-ordered
#define WS_FLAG   69166080u   // u32: 0 = whole sequence certified silent

#define VMW0() asm volatile("s_waitcnt vmcnt(0)" ::: "memory")

// ---------------------------------------------------------------- setup ----
// one WAVE per (dir,row): coalesced mask reads + ballot compaction.
// Also zeroes FLAG and the loss slot (replaces two memsets); WiT entries are
// written unconditionally (select) so the WiT memset is gone too.
__global__ __launch_bounds__(256) void build_tables(
    const float* __restrict__ w_fw, const float* __restrict__ b_fw,
    const float* __restrict__ tau_n_fw, const float* __restrict__ mask_fw,
    const float* __restrict__ w_bw, const float* __restrict__ b_bw,
    const float* __restrict__ tau_n_bw, const float* __restrict__ mask_bw,
    const float* __restrict__ tau_m_fw, const float* __restrict__ tau_m_bw,
    float* __restrict__ WiT, float* __restrict__ Wspk, u16* __restrict__ OFFspk,
    float* __restrict__ CBIAS, float* __restrict__ BETA, float* __restrict__ ALPHA,
    u32* __restrict__ flagp, float* __restrict__ lossp)
{
  if (blockIdx.x == 0 && threadIdx.x == 0) { *flagp = 0u; *lossp = 0.0f; }
  const int row = blockIdx.x * 4 + (threadIdx.x >> 6);   // 0..4095
  const int l = threadIdx.x & 63;
  const int dir = row >> 11, r = row & (NB - 1);
  const float* w  = dir ? w_bw : w_fw;
  const float* mk = dir ? mask_bw : mask_fw;
  float* wit = WiT + (size_t)dir * (NIN * NB);
  float* wsp = Wspk + (size_t)dir * (NSYN * NB);
  u16*   osp = OFFspk + (size_t)dir * (NSYN * NB);
  const u64 ltm = (1ull << l) - 1ull;
  int sc = 0;
#pragma unroll
  for (int ch = 0; ch < 5; ++ch) {
    const int j = ch * 64 + l;
    const float m = (j < KS) ? mk[(size_t)r * KS + j] : 0.0f;
    const u64 bits = __ballot(m != 0.0f);
    const u64 sbits = (ch == 0) ? ((bits >> NIN) << NIN) : bits;  // entries j>=39
    if (ch == 0 && j < NIN) {
      wit[(size_t)j * NB + r] = (m != 0.0f) ? w[(size_t)r * KS + j] : 0.0f;
    } else if (m != 0.0f) {
      const int pos = sc + (int)__popcll(sbits & ltm);
      if (pos < NSYN) {
        wsp[(size_t)pos * NB + r] = w[(size_t)r * KS + j];
        osp[(size_t)pos * NB + r] = (u16)((j - NIN) * 4);
      }
    }
    sc += (int)__popcll(sbits);
  }
  for (int p = sc + l; p < NSYN; p += 64) {   // pad -> permanent-zero slot
    wsp[(size_t)p * NB + r] = 0.0f;
    osp[(size_t)p * NB + r] = (u16)(256 * 4);
  }
  if (l == 0) {
    const float* tn = dir ? tau_n_bw : tau_n_fw;
    const float* bb = dir ? b_bw : b_fw;
    BETA[dir * NB + r]  = 1.0f / (1.0f + expf(-tn[r]));
    CBIAS[dir * NB + r] = bb[r];
    if (r < HID) {
      const float* tm = dir ? tau_m_bw : tau_m_fw;
      ALPHA[dir * HID + r] = 1.0f / (1.0f + expf(-tm[r]));
    }
  }
}

// --------------------------------------------- per-frame input lin (fp16) ----
// TWO commit-blocks per workgroup: per wv load (8 floats) we now do 2 frames x
// 4 batches x 8 = 64 FMA. grid: bid 0..99 fw pairs, 100..200 bw pairs.
// Per-element math identical to the 1-frame version (same accumulation order).
__global__ __launch_bounds__(256) void lin_precompute(
    const float* __restrict__ x, const float* __restrict__ WiT,
    const float* __restrict__ CBIAS, u16* __restrict__ LINH)
{
  const int bid = blockIdx.x;
  int dir, c0, nf;
  if (bid < 100) { dir = 0; c0 = bid * 2; nf = 2; }
  else { dir = 1; c0 = (bid - 100) * 2; nf = (c0 == 200) ? 1 : 2; }
  const int t = threadIdx.x;
  const int r0 = t * 8;
  __shared__ float xs[2][32 * NIN];
  for (int f = 0; f < nf; ++f) {
    const int c = c0 + f;
    const int fr = (dir == 0) ? c : ((c == 0) ? 0 : 200 - c);
    for (int i = t; i < 32 * NIN; i += 256) {
      const int b = i / NIN, cc = i - b * NIN;
      xs[f][i] = x[(size_t)b * (SFRAMES * NIN) + fr * NIN + cc];
    }
  }
  __syncthreads();
  const float* wit = WiT + (size_t)dir * (NIN * NB) + r0;
  float bias[8];
  *reinterpret_cast<float4*>(&bias[0]) = *reinterpret_cast<const float4*>(CBIAS + dir * NB + r0);
  *reinterpret_cast<float4*>(&bias[4]) = *reinterpret_cast<const float4*>(CBIAS + dir * NB + r0 + 4);
  const int lpos = ((t & 3) * 64 + (t >> 2)) * 8;   // permuted offset
#pragma unroll 1
  for (int bt = 0; bt < 8; ++bt) {
    float acc[2][4][8];
#pragma unroll
    for (int f = 0; f < 2; ++f)
#pragma unroll
      for (int q = 0; q < 4; ++q)
#pragma unroll
        for (int k = 0; k < 8; ++k) acc[f][q][k] = 0.0f;
#pragma unroll 1
    for (int cc = 0; cc < NIN; ++cc) {
      float wv[8];
      *reinterpret_cast<float4*>(&wv[0]) = *reinterpret_cast<const float4*>(wit + cc * NB);
      *reinterpret_cast<float4*>(&wv[4]) = *reinterpret_cast<const float4*>(wit + cc * NB + 4);
#pragma unroll
      for (int f = 0; f < 2; ++f)
#pragma unroll
        for (int q = 0; q < 4; ++q) {
          const float sx = xs[f][(bt * 4 + q) * NIN + cc];
#pragma unroll
          for (int k = 0; k < 8; ++k) acc[f][q][k] += wv[k] * sx;
        }
    }
#pragma unroll
    for (int f = 0; f < 2; ++f) {
      if (f >= nf) break;
#pragma unroll
      for (int q = 0; q < 4; ++q) {
        const int b = bt * 4 + q;
        u16* dst = LINH + ((size_t)(dir * 32 + b) * NBLK + (c0 + f)) * NB + lpos;
        union { u16 h[8]; uint4 u; } pk;
#pragma unroll
        for (int k = 0; k < 8; ++k) {
          const _Float16 hv = (_Float16)(acc[f][q][k] + bias[k]);
          pk.h[k] = *reinterpret_cast<const u16*>(&hv);
        }
        *reinterpret_cast<uint4*>(dst) = pk.u;
      }
    }
  }
}

// -------------------------------------------- parallel silent certificate ----
// One thread per (chain, neuron): replays the serial scan's fast-path math
// BITWISE for all 2000 steps; global running max replaces per-window checks
// (same decision: any step with mem > 1 anywhere => fail).
__global__ __launch_bounds__(256) void cert_scan(
    const u16* __restrict__ LINH, const float* __restrict__ BETA,
    const float* __restrict__ ALPHA, u32* __restrict__ flag)
{
  const int chain = blockIdx.x;
  const int dir = chain >> 5;
  const int tid = threadIdx.x;          // == q*64 + l  (matches LINH layout)
  const int l = tid & 63, q = tid >> 6;

  v2f e2[4], be2[4];
  const v2f* bp = reinterpret_cast<const v2f*>(BETA + dir * NB + l * 32 + q * 8);
#pragma unroll
  for (int i = 0; i < 4; ++i) { be2[i] = bp[i]; e2[i] = (v2f){0.f, 0.f}; }
  const float al = ALPHA[dir * HID + l * 4 + q];
  const float om = 1.0f - al;
  const float sp = 0.0f;

  float Sl = 0.0f, mem = 0.0f, mmax = -1e30f;
  uint4 lino = {0u, 0u, 0u, 0u};

  const u16* LB = LINH + (size_t)chain * NBLK * NB;
  auto ld = [&](int c) {
    return *reinterpret_cast<const uint4*>(LB + (size_t)c * NB + tid * 8);
  };
  auto tree8 = [](const v2f v[4]) -> float {
    const v2f a = v[0] + v[1];
    const v2f b = v[2] + v[3];
    const v2f t = a + b;
    return t.x + t.y;
  };
  auto commit = [&](uint4 vn) {
    const _Float16* hn = reinterpret_cast<const _Float16*>(&vn);
    const _Float16* ho = reinterpret_cast<const _Float16*>(&lino);
    v2f ln2[4];
#pragma unroll
    for (int i = 0; i < 4; ++i) {
      const float fn0 = (float)hn[2 * i], fn1 = (float)hn[2 * i + 1];
      v2f dd; dd.x = (float)ho[2 * i] - fn0; dd.y = (float)ho[2 * i + 1] - fn1;
      e2[i] += dd;
      ln2[i].x = fn0; ln2[i].y = fn1;
    }
    Sl = tree8(ln2);
    lino = vn;
  };
  auto fstep = [&]() {
#pragma unroll
    for (int i = 0; i < 4; ++i) e2[i] *= be2[i];
    const float esum = tree8(e2);
    const float dsum = esum + Sl;
    mem = fmaf(al, mem, fmaf(om, dsum, -sp));
    mmax = fmaxf(mmax, mem);
  };

  uint4 p0 = ld(0), p1 = ld(1);

  if (dir == 0) {
#pragma unroll 1
    for (int w = 0; w < SFRAMES; w += 2) {
      commit(p0); p0 = ld(w + 2);
#pragma unroll
      for (int t = 0; t < 10; ++t) fstep();
      commit(p1); p1 = ld(w + 3);
#pragma unroll
      for (int t = 0; t < 10; ++t) fstep();
    }
  } else {
    commit(p0); p0 = ld(2);
    fstep();
    commit(p1); p1 = ld(3);
#pragma unroll
    for (int t = 0; t < 9; ++t) fstep();
#pragma unroll 1
    for (int w = 1; w < 199; w += 2) {
      fstep();
      commit(p0); p0 = ld(w + 3);
#pragma unroll
      for (int t = 0; t < 9; ++t) fstep();
      fstep();
      commit(p1); p1 = ld(w + 4);
#pragma unroll
      for (int t = 0; t < 9; ++t) fstep();
    }
    fstep();
    commit(p0);
#pragma unroll
    for (int t = 0; t < 9; ++t) fstep();
  }

  const bool fail = (mmax > 1.0f);
  if (__any(fail ? 1 : 0) && (tid & 63) == 0) atomicOr(flag, 1u);
}

// ------------------------------------------------------- recurrent core ----
__device__ __forceinline__ void gload_lds16(const void* g, void* l) {
  __builtin_amdgcn_global_load_lds(
      (const __attribute__((address_space(1))) void*)g,
      (__attribute__((address_space(3))) void*)l, 16, 0, 0);
}

// grid = 64 chains (dir*32 + b), block = 64 (ONE wave). Early-exits when the
// cert kernel proved the whole sequence silent (FRAMES pre-zeroed by memset).
__global__ __launch_bounds__(64, 1) void snn_scan(
    const u16* __restrict__ LINH, const float* __restrict__ Wspk,
    const u16* __restrict__ OFFspk, const float* __restrict__ BETA,
    const float* __restrict__ ALPHA, float* __restrict__ FRAMES,
    const u32* __restrict__ flag)
{
  if (*flag == 0u) return;     // certified silent: FRAMES==0 already correct

  const int chain = blockIdx.x;
  const int dir = chain >> 5;
  const int l = threadIdx.x;

  __shared__ __align__(16) u16 ring[4][NB];   // lin fp16 4-slot ring
  __shared__ __align__(16) float spkbuf[260]; // spikes; slots 256..259 stay 0

  {
    const float4 z4 = {0.f, 0.f, 0.f, 0.f};
    *reinterpret_cast<float4*>(&spkbuf[l * 4]) = z4;
    if (l == 0) *reinterpret_cast<float4*>(&spkbuf[256]) = z4;
    const uint4 zu = {0u, 0u, 0u, 0u};
    uint4* zz = reinterpret_cast<uint4*>(&ring[3][l * 32]);   // lin(-1) = 0
    zz[0] = zu; zz[1] = zu; zz[2] = zu; zz[3] = zu;
  }

  v2f e2[4][4], be2[4][4];
  float Sl[4] = {0.f, 0.f, 0.f, 0.f};
  float mem[4] = {0.f, 0.f, 0.f, 0.f};
  float sp[4] = {0.f, 0.f, 0.f, 0.f};
  float al[4], om[4];
#pragma unroll
  for (int q = 0; q < 4; ++q) {
    const v2f* bp = reinterpret_cast<const v2f*>(BETA + dir * NB + l * 32 + q * 8);
#pragma unroll
    for (int i = 0; i < 4; ++i) { be2[q][i] = bp[i]; e2[q][i] = (v2f){0.f, 0.f}; }
    al[q] = ALPHA[dir * HID + l * 4 + q];
    om[q] = 1.0f - al[q];
  }

  const u16* LB = LINH + (size_t)chain * NBLK * NB;
#pragma unroll
  for (int i = 0; i < 4; ++i) {
    gload_lds16(LB + 0 * NB + i * 512 + l * 8, &ring[0][i * 512]);
    gload_lds16(LB + 1 * NB + i * 512 + l * 8, &ring[1][i * 512]);
  }

  const float* wsp = Wspk + (size_t)dir * (NSYN * NB) + l * 32;
  const u16*  ofp = OFFspk + (size_t)dir * (NSYN * NB) + l * 32;
  float* frow = FRAMES + (size_t)chain * (SFRAMES * HID) + l * 4;

  int F = 0, c = 0;
  float mmax[4], facc[4];
  float4 pend = {0.f, 0.f, 0.f, 0.f};

  auto tree8 = [](const v2f v[4]) -> float {
    const v2f a = v[0] + v[1];
    const v2f b = v[2] + v[3];
    const v2f t = a + b;
    return t.x + t.y;
  };

  auto commit = [&](bool dopref) {
    const int sn = c & 3, so = (c + 3) & 3;
#pragma unroll
    for (int q = 0; q < 4; ++q) {
      const uint4 vn = *reinterpret_cast<const uint4*>(&ring[sn][(q * 64 + l) * 8]);
      const uint4 vo = *reinterpret_cast<const uint4*>(&ring[so][(q * 64 + l) * 8]);
      const _Float16* hn = reinterpret_cast<const _Float16*>(&vn);
      const _Float16* ho = reinterpret_cast<const _Float16*>(&vo);
      v2f ln2[4];
#pragma unroll
      for (int i = 0; i < 4; ++i) {
        const float fn0 = (float)hn[2 * i], fn1 = (float)hn[2 * i + 1];
        v2f dd; dd.x = (float)ho[2 * i] - fn0; dd.y = (float)ho[2 * i + 1] - fn1;
        e2[q][i] += dd;
        ln2[i].x = fn0; ln2[i].y = fn1;
      }
      Sl[q] = tree8(ln2);
    }
    if (dopref) {                       // prefetch 2 blocks ahead; slot disjoint
      const u16* src = LB + (size_t)(c + 2) * NB;
      u16* dst = &ring[(c + 2) & 3][0];
#pragma unroll
      for (int i = 0; i < 4; ++i)
        gload_lds16(src + i * 512 + l * 8, dst + i * 512);
    }
    ++c;
  };

  auto fstep = [&]() {
#pragma unroll
    for (int q = 0; q < 4; ++q)
#pragma unroll
      for (int i = 0; i < 4; ++i) e2[q][i] *= be2[q][i];
#pragma unroll
    for (int q = 0; q < 4; ++q) {
      const float esum = tree8(e2[q]);
      const float dsum = esum + Sl[q];
      mem[q] = fmaf(al[q], mem[q], fmaf(om[q], dsum, -sp[q]));
      mmax[q] = fmaxf(mmax[q], mem[q]);
    }
  };

  auto sstep = [&]() {
    if (__builtin_expect(F, 0)) {       // spikes live: exact gather
      float scv[4][8];
#pragma unroll
      for (int q = 0; q < 4; ++q)
#pragma unroll
        for (int j = 0; j < 8; ++j) scv[q][j] = 0.0f;
      const char* kb = reinterpret_cast<const char*>(&spkbuf[0]);
#pragma unroll 1
      for (int s = 0; s < NSYN; ++s) {
#pragma unroll
        for (int q = 0; q < 4; ++q) {
          float wv[8];
          *reinterpret_cast<float4*>(&wv[0]) =
              *reinterpret_cast<const float4*>(wsp + (size_t)s * NB + q * 8);
          *reinterpret_cast<float4*>(&wv[4]) =
              *reinterpret_cast<const float4*>(wsp + (size_t)s * NB + q * 8 + 4);
          const uint4 ov = *reinterpret_cast<const uint4*>(ofp + (size_t)s * NB + q * 8);
          const u16* of = reinterpret_cast<const u16*>(&ov);
#pragma unroll
          for (int j = 0; j < 8; ++j)
            scv[q][j] += wv[j] * *reinterpret_cast<const float*>(kb + of[j]);
        }
      }
#pragma unroll
      for (int q = 0; q < 4; ++q)
#pragma unroll
        for (int i = 0; i < 4; ++i) {
          v2f sc2; sc2.x = scv[q][2 * i]; sc2.y = scv[q][2 * i + 1];
          const v2f one = {1.0f, 1.0f};
          e2[q][i] = be2[q][i] * e2[q][i] + (one - be2[q][i]) * sc2;
        }
    } else {                            // silent: identical to fstep core
#pragma unroll
      for (int q = 0; q < 4; ++q)
#pragma unroll
        for (int i = 0; i < 4; ++i) e2[q][i] *= be2[q][i];
    }
    float ssum = 0.0f;
#pragma unroll
    for (int q = 0; q < 4; ++q) {
      const float esum = tree8(e2[q]);
      const float dsum = esum + Sl[q];
      mem[q] = fmaf(al[q], mem[q], fmaf(om[q], dsum, -sp[q]));
      sp[q] = (mem[q] > 1.0f) ? 1.0f : 0.0f;
      facc[q] += sp[q];
      ssum += sp[q];
    }
    const float4 sv = {sp[0], sp[1], sp[2], sp[3]};
    *reinterpret_cast<float4*>(&spkbuf[l * 4]) = sv;
    F = __any(ssum > 0.0f);
  };

#pragma unroll 1
  for (int w = 0; w < SFRAMES; ++w) {
    // save window-start state for possible slow redo
    v2f es[4][4]; float Sls[4], mems_[4], sps[4];
#pragma unroll
    for (int q = 0; q < 4; ++q) {
#pragma unroll
      for (int i = 0; i < 4; ++i) es[q][i] = e2[q][i];
      Sls[q] = Sl[q]; mems_[q] = mem[q]; sps[q] = sp[q];
    }
    const int cs = c;
    bool slow = (F != 0);
    bool prefed = false;

    if (!slow) {
      prefed = true;
      mmax[0] = mmax[1] = mmax[2] = mmax[3] = -1e30f;
      if (dir == 0) {
        VMW0(); commit(true);
        if (w) *reinterpret_cast<float4*>(frow + (w - 1) * HID) = pend;
#pragma unroll
        for (int t = 0; t < 10; ++t) fstep();
      } else {
        if (w == 0) { VMW0(); commit(true); }
        fstep();
        VMW0(); commit(true);
        if (w) *reinterpret_cast<float4*>(frow + (w - 1) * HID) = pend;
#pragma unroll
        for (int t = 0; t < 9; ++t) fstep();
      }
      const int viol = (mmax[0] > 1.0f) || (mmax[1] > 1.0f) ||
                       (mmax[2] > 1.0f) || (mmax[3] > 1.0f);
      slow = (__any(viol) != 0);
      if (!slow) {
        pend = (float4){0.f, 0.f, 0.f, 0.f};   // facc = 0 exactly
      } else {                                  // restore + redo
#pragma unroll
        for (int q = 0; q < 4; ++q) {
#pragma unroll
          for (int i = 0; i < 4; ++i) e2[q][i] = es[q][i];
          Sl[q] = Sls[q]; mem[q] = mems_[q]; sp[q] = sps[q];
        }
        c = cs;
      }
    }
    if (slow) {
      facc[0] = facc[1] = facc[2] = facc[3] = 0.0f;
      if (dir == 0) {
        VMW0(); commit(!prefed);
        if (w) *reinterpret_cast<float4*>(frow + (w - 1) * HID) = pend;
#pragma unroll 1
        for (int t = 0; t < 10; ++t) sstep();
      } else {
        if (w == 0) { VMW0(); commit(!prefed); }
        sstep();
        VMW0(); commit(!prefed);
        if (w) *reinterpret_cast<float4*>(frow + (w - 1) * HID) = pend;
#pragma unroll 1
        for (int t = 0; t < 9; ++t) sstep();
      }
      pend = (float4){facc[0] * 0.1f, facc[1] * 0.1f, facc[2] * 0.1f, facc[3] * 0.1f};
    }
  }
  *reinterpret_cast<float4*>(frow + (SFRAMES - 1) * HID) = pend;
}

// ------------------------------------------------------------- readout ----
__global__ __launch_bounds__(256) void ro_matmul(
    const float* __restrict__ FRAMES, const float* __restrict__ w_ro,
    const float* __restrict__ b_ro, float* __restrict__ Y,
    const u32* __restrict__ flag)
{
  const int bid = blockIdx.x;
  const int s = bid >> 1, b0 = (bid & 1) * 16;

  if (*flag == 0u) {   // certified silent: FRAMES==0 -> Y = b_ro broadcast
    for (int i = threadIdx.x; i < 16 * OUTC; i += 256) {
      const int rb = i / OUTC, o = i - rb * OUTC;
      Y[((size_t)s * 32 + b0 + rb) * OUTC + o] = b_ro[o];
    }
    return;
  }

  __shared__ float rowc[16 * 132];
  __shared__ float wlds[48 * 132];
  const int bb = threadIdx.x >> 4;
  const int oc = threadIdx.x & 15;
  const int o1 = oc + 16, o2 = oc + 32;
  float a0 = 0.f, a1 = 0.f, a2 = 0.f;
  const bool u2 = (o2 < OUTC);

#pragma unroll 1
  for (int kc = 0; kc < 4; ++kc) {
    for (int i = threadIdx.x; i < 16 * 128; i += 256) {
      const int rb = i >> 7, kk = i & 127;
      float v;
      if (kc < 2)
        v = FRAMES[((size_t)(b0 + rb) * SFRAMES + s) * HID + kc * 128 + kk];
      else
        v = FRAMES[((size_t)(32 + b0 + rb) * SFRAMES + (199 - s)) * HID + (kc - 2) * 128 + kk];
      rowc[rb * 132 + kk] = v;
    }
    for (int i = threadIdx.x; i < OUTC * 128; i += 256) {
      const int o = i >> 7, kk = i & 127;
      wlds[o * 132 + kk] = w_ro[(size_t)o * 512 + kc * 128 + kk];
    }
    __syncthreads();

    const float* rp = &rowc[bb * 132];
    const float* w0 = &wlds[oc * 132];
    const float* w1 = &wlds[o1 * 132];
    const float* w2 = &wlds[o2 * 132];
#pragma unroll 8
    for (int kk = 0; kk < 128; kk += 4) {
      const float4 a  = *reinterpret_cast<const float4*>(rp + kk);
      const float4 v0 = *reinterpret_cast<const float4*>(w0 + kk);
      const float4 v1 = *reinterpret_cast<const float4*>(w1 + kk);
      const float4 v2 = *reinterpret_cast<const float4*>(w2 + kk);
      a0 = fmaf(a.x, v0.x, fmaf(a.y, v0.y, fmaf(a.z, v0.z, fmaf(a.w, v0.w, a0))));
      a1 = fmaf(a.x, v1.x, fmaf(a.y, v1.y, fmaf(a.z, v1.z, fmaf(a.w, v1.w, a1))));
      if (u2)
        a2 = fmaf(a.x, v2.x, fmaf(a.y, v2.y, fmaf(a.z, v2.z, fmaf(a.w, v2.w, a2))));
    }
    __syncthreads();
  }

  float* yp = Y + ((size_t)s * 32 + b0 + bb) * OUTC;
  yp[oc] = a0 + b_ro[oc];
  yp[o1] = a1 + b_ro[o1];
  if (u2) yp[o2] = a2 + b_ro[o2];
}

__global__ __launch_bounds__(256) void ro_scan(
    const float* __restrict__ Y, const float* __restrict__ tau_ro,
    const int* __restrict__ labels, float* __restrict__ out)
{
  const int b = blockIdx.x;
  const int tid = threadIdx.x;
  __shared__ float buf[SFRAMES * 40];
  __shared__ float lsum[256];
  for (int i = tid; i < SFRAMES * OUTC; i += 256) {
    const int s = i / OUTC, o = i - s * OUTC;
    buf[s * 40 + o] = Y[((size_t)s * 32 + b) * OUTC + o];
  }
  __syncthreads();
  if (tid < OUTC) {
    const float ar = 1.0f / (1.0f + expf(-tau_ro[tid]));
    const float omr = 1.0f - ar;
    float m = 0.0f;
#pragma unroll 4
    for (int s = 0; s < SFRAMES; ++s) {
      m = ar * m + omr * buf[s * 40 + tid];
      buf[s * 40 + tid] = m;
    }
  }
  __syncthreads();
  float nacc = 0.0f;
  for (int s = tid; s < SFRAMES; s += 256) {
    float mx = -1e30f;
    for (int j = 0; j < OUTC; ++j) mx = fmaxf(mx, buf[s * 40 + j]);
    float se = 0.0f;
    for (int j = 0; j < OUTC; ++j) se += expf(buf[s * 40 + j] - mx);
    const float lse = logf(se);
    float* op = out + ((size_t)s * 32 + b) * OUTC;
    for (int j = 0; j < OUTC; ++j) op[j] = buf[s * 40 + j] - mx - lse;
    const int lab = labels[b * SFRAMES + s];
    nacc += -(buf[s * 40 + lab] - mx - lse);
  }
  lsum[tid] = nacc;
  __syncthreads();
  for (int off = 128; off > 0; off >>= 1) {
    if (tid < off) lsum[tid] += lsum[tid + off];
    __syncthreads();
  }
  if (tid == 0) atomicAdd(out + SFRAMES * 32 * OUTC, lsum[0] * (1.0f / 32.0f));
}

// -------------------------------------------------------------- launch ----
extern "C" void kernel_launch(void* const* d_in, const int* in_sizes, int n_in,
                              void* d_out, int out_size, void* d_ws, size_t ws_size,
                              hipStream_t stream)
{
  const float* x        = (const float*)d_in[0];
  const int*   labels   = (const int*)d_in[1];
  const float* w_fw     = (const float*)d_in[2];
  const float* b_fw     = (const float*)d_in[3];
  const float* tau_m_fw = (const float*)d_in[4];
  const float* tau_n_fw = (const float*)d_in[5];
  const float* mask_fw  = (const float*)d_in[6];
  const float* w_bw     = (const float*)d_in[7];
  const float* b_bw     = (const float*)d_in[8];
  const float* tau_m_bw = (const float*)d_in[9];
  const float* tau_n_bw = (const float*)d_in[10];
  const float* mask_bw  = (const float*)d_in[11];
  const float* w_ro     = (const float*)d_in[12];
  const float* b_ro     = (const float*)d_in[13];
  const float* tau_m_ro = (const float*)d_in[14];
  float* out = (float*)d_out;

  char* ws = (char*)d_ws;
  float* WiT    = (float*)(ws + WS_WIT);
  float* Wspk   = (float*)(ws + WS_WSPK);
  u16*   OFFspk = (u16*)(ws + WS_OFFSPK);
  float* CBIAS  = (float*)(ws + WS_CBIAS);
  float* BETA   = (float*)(ws + WS_BETA);
  float* ALPHA  = (float*)(ws + WS_ALPHA);
  float* FRAMES = (float*)(ws + WS_FRAMES);
  float* Y      = (float*)(ws + WS_Y);
  u16*   LINH   = (u16*)(ws + WS_LINH);
  u32*   FLAG   = (u32*)(ws + WS_FLAG);

  hipMemsetAsync(FRAMES, 0, 13107200u, stream);      // correct output if silent

  build_tables<<<1024, 256, 0, stream>>>(w_fw, b_fw, tau_n_fw, mask_fw,
                                         w_bw, b_bw, tau_n_bw, mask_bw,
                                         tau_m_fw, tau_m_bw,
                                         WiT, Wspk, OFFspk, CBIAS, BETA, ALPHA,
                                         FLAG, out + SFRAMES * 32 * OUTC);
  lin_precompute<<<201, 256, 0, stream>>>(x, WiT, CBIAS, LINH);
  cert_scan<<<64, 256, 0, stream>>>(LINH, BETA, ALPHA, FLAG);
  snn_scan<<<64, 64, 0, stream>>>(LINH, Wspk, OFFspk, BETA, ALPHA, FRAMES, FLAG);
  ro_matmul<<<2 * SFRAMES, 256, 0, stream>>>(FRAMES, w_ro, b_ro, Y, FLAG);
  ro_scan<<<32, 256, 0, stream>>>(Y, tau_m_ro, labels, out);
}

// Round 11
// 113.872 us; speedup vs baseline: 9.4623x; 1.6211x over previous
//
#include <hip/hip_runtime.h>
#include <math.h>

typedef unsigned short u16;
typedef unsigned int u32;
typedef unsigned long long u64;
typedef float v2f __attribute__((ext_vector_type(2)));

#define NSYN 37
#define NB   2048
#define KS   296
#define NIN  39
#define TSTEPS 2000
#define SFRAMES 200
#define HID 256
#define OUTC 39
#define NBLK 204          // LIN blocks alloc'd per chain (fw uses 200, bw 201, pad)

// ws layout (byte offsets, 16B aligned)
#define WS_WIT    0u          // float [2][39][2048] dense input weights (transposed)
#define WS_WSPK   638976u     // float [2][37][2048] spike-synapse weights
#define WS_OFFSPK 1245184u    // u16   [2][37][2048] spike LDS byte offsets
#define WS_CBIAS  1548288u    // float [2][2048]     raw bias
#define WS_BETA   1564672u    // float [2][2048]
#define WS_ALPHA  1581056u    // float [2][256]
#define WS_FRAMES 1583104u    // float [2][32][200][256]
#define WS_Y      14690304u   // float [200][32][39]
#define WS_LINH   15688704u   // u16/fp16 [64 chains][204 blocks][2048] NATURAL branch order
#define WS_FLAG   69166080u   // u32: 0 = whole sequence certified silent

#define VMW0() asm volatile("s_waitcnt vmcnt(0)" ::: "memory")

// ---------------------------------------------------------------- setup ----
// one WAVE per (dir,row): coalesced mask reads + ballot compaction.
// Also zeroes FLAG and the loss slot; WiT entries written unconditionally.
__global__ __launch_bounds__(256) void build_tables(
    const float* __restrict__ w_fw, const float* __restrict__ b_fw,
    const float* __restrict__ tau_n_fw, const float* __restrict__ mask_fw,
    const float* __restrict__ w_bw, const float* __restrict__ b_bw,
    const float* __restrict__ tau_n_bw, const float* __restrict__ mask_bw,
    const float* __restrict__ tau_m_fw, const float* __restrict__ tau_m_bw,
    float* __restrict__ WiT, float* __restrict__ Wspk, u16* __restrict__ OFFspk,
    float* __restrict__ CBIAS, float* __restrict__ BETA, float* __restrict__ ALPHA,
    u32* __restrict__ flagp, float* __restrict__ lossp)
{
  if (blockIdx.x == 0 && threadIdx.x == 0) { *flagp = 0u; *lossp = 0.0f; }
  const int row = blockIdx.x * 4 + (threadIdx.x >> 6);   // 0..4095
  const int l = threadIdx.x & 63;
  const int dir = row >> 11, r = row & (NB - 1);
  const float* w  = dir ? w_bw : w_fw;
  const float* mk = dir ? mask_bw : mask_fw;
  float* wit = WiT + (size_t)dir * (NIN * NB);
  float* wsp = Wspk + (size_t)dir * (NSYN * NB);
  u16*   osp = OFFspk + (size_t)dir * (NSYN * NB);
  const u64 ltm = (1ull << l) - 1ull;
  int sc = 0;
#pragma unroll
  for (int ch = 0; ch < 5; ++ch) {
    const int j = ch * 64 + l;
    const float m = (j < KS) ? mk[(size_t)r * KS + j] : 0.0f;
    const u64 bits = __ballot(m != 0.0f);
    const u64 sbits = (ch == 0) ? ((bits >> NIN) << NIN) : bits;  // entries j>=39
    if (ch == 0 && j < NIN) {
      wit[(size_t)j * NB + r] = (m != 0.0f) ? w[(size_t)r * KS + j] : 0.0f;
    } else if (m != 0.0f) {
      const int pos = sc + (int)__popcll(sbits & ltm);
      if (pos < NSYN) {
        wsp[(size_t)pos * NB + r] = w[(size_t)r * KS + j];
        osp[(size_t)pos * NB + r] = (u16)((j - NIN) * 4);
      }
    }
    sc += (int)__popcll(sbits);
  }
  for (int p = sc + l; p < NSYN; p += 64) {   // pad -> permanent-zero slot
    wsp[(size_t)p * NB + r] = 0.0f;
    osp[(size_t)p * NB + r] = (u16)(256 * 4);
  }
  if (l == 0) {
    const float* tn = dir ? tau_n_bw : tau_n_fw;
    const float* bb = dir ? b_bw : b_fw;
    BETA[dir * NB + r]  = 1.0f / (1.0f + expf(-tn[r]));
    CBIAS[dir * NB + r] = bb[r];
    if (r < HID) {
      const float* tm = dir ? tau_m_bw : tau_m_fw;
      ALPHA[dir * HID + r] = 1.0f / (1.0f + expf(-tm[r]));
    }
  }
}

// --------------------------------------------- per-frame input lin (fp16) ----
// GEMM-tiled, NATURAL branch order. grid = 401 c-values x 4 batch-groups;
// block = 512 threads, thread t owns branches t*4..t*4+3 (acc[8][4] = 32 regs,
// spill-proof); 8 (b,frame) pairs share each weight load -> 32 FMA / float4.
// Writes: per pair a contiguous 4KB row; per thread uint2 (8B) coalesced.
__global__ __launch_bounds__(512) void lin_gemm(
    const float* __restrict__ x, const float* __restrict__ WiT,
    const float* __restrict__ CBIAS, u16* __restrict__ LINH)
{
  const int bid = blockIdx.x;          // 0..1603
  const int cidx = bid >> 2, bg = bid & 3;
  const int dir = (cidx < 200) ? 0 : 1;
  const int c = (dir == 0) ? cidx : (cidx - 200);
  const int fr = (dir == 0) ? c : ((c == 0) ? 0 : 200 - c);
  const int b0 = bg * 8;
  const int t = threadIdx.x;

  __shared__ float xs[NIN * 8];        // xs[cc*8 + p], transposed for b128 reads
  if (t < NIN * 8) {
    const int cc = t >> 3, p = t & 7;
    xs[t] = x[(size_t)(b0 + p) * (SFRAMES * NIN) + fr * NIN + cc];
  }
  __syncthreads();

  const float* wit = WiT + (size_t)dir * (NIN * NB) + t * 4;
  const float4 bv = *reinterpret_cast<const float4*>(CBIAS + dir * NB + t * 4);
  const float bias4[4] = {bv.x, bv.y, bv.z, bv.w};

  float acc[8][4];
#pragma unroll
  for (int p = 0; p < 8; ++p)
#pragma unroll
    for (int k = 0; k < 4; ++k) acc[p][k] = 0.0f;

#pragma unroll 1
  for (int cc = 0; cc < NIN; ++cc) {
    const float4 wv = *reinterpret_cast<const float4*>(wit + (size_t)cc * NB);
    const float4 s0 = *reinterpret_cast<const float4*>(&xs[cc * 8]);
    const float4 s1 = *reinterpret_cast<const float4*>(&xs[cc * 8 + 4]);
    const float sxa[8] = {s0.x, s0.y, s0.z, s0.w, s1.x, s1.y, s1.z, s1.w};
#pragma unroll
    for (int p = 0; p < 8; ++p) {
      acc[p][0] = fmaf(wv.x, sxa[p], acc[p][0]);
      acc[p][1] = fmaf(wv.y, sxa[p], acc[p][1]);
      acc[p][2] = fmaf(wv.z, sxa[p], acc[p][2]);
      acc[p][3] = fmaf(wv.w, sxa[p], acc[p][3]);
    }
  }

#pragma unroll
  for (int p = 0; p < 8; ++p) {
    u16* dst = LINH + ((size_t)(dir * 32 + b0 + p) * NBLK + c) * NB + t * 4;
    union { u16 h[4]; uint2 u; } pk;
#pragma unroll
    for (int k = 0; k < 4; ++k) {
      const _Float16 hv = (_Float16)(acc[p][k] + bias4[k]);
      pk.h[k] = *reinterpret_cast<const u16*>(&hv);
    }
    *reinterpret_cast<uint2*>(dst) = pk.u;
  }
}

// -------------------------------------------- parallel silent certificate ----
// One thread per (chain, neuron), natural layout: thread reads its neuron's 8
// branches as one coalesced uint4 at nrn*8. Replays the serial scan's fast
// path BITWISE (same expression trees); global running max.
// grid = 256 blocks (chain*4 + quarter) x 64 threads.
__global__ __launch_bounds__(64) void cert_scan(
    const u16* __restrict__ LINH, const float* __restrict__ BETA,
    const float* __restrict__ ALPHA, u32* __restrict__ flag)
{
  const int bid = blockIdx.x;
  const int chain = bid >> 2;
  const int dir = chain >> 5;
  const int nrn = (bid & 3) * 64 + threadIdx.x;   // 0..255

  v2f e2[4], be2[4];
  const v2f* bp = reinterpret_cast<const v2f*>(BETA + dir * NB + nrn * 8);
#pragma unroll
  for (int i = 0; i < 4; ++i) { be2[i] = bp[i]; e2[i] = (v2f){0.f, 0.f}; }
  const float al = ALPHA[dir * HID + nrn];
  const float om = 1.0f - al;
  const float sp = 0.0f;

  float Sl = 0.0f, mem = 0.0f, mmax = -1e30f;
  uint4 lino = {0u, 0u, 0u, 0u};

  const u16* LB = LINH + (size_t)chain * NBLK * NB;
  auto ld = [&](int c) {
    return *reinterpret_cast<const uint4*>(LB + (size_t)c * NB + nrn * 8);
  };
  auto tree8 = [](const v2f v[4]) -> float {
    const v2f a = v[0] + v[1];
    const v2f b = v[2] + v[3];
    const v2f t = a + b;
    return t.x + t.y;
  };
  auto commit = [&](uint4 vn) {
    const _Float16* hn = reinterpret_cast<const _Float16*>(&vn);
    const _Float16* ho = reinterpret_cast<const _Float16*>(&lino);
    v2f ln2[4];
#pragma unroll
    for (int i = 0; i < 4; ++i) {
      const float fn0 = (float)hn[2 * i], fn1 = (float)hn[2 * i + 1];
      v2f dd; dd.x = (float)ho[2 * i] - fn0; dd.y = (float)ho[2 * i + 1] - fn1;
      e2[i] += dd;
      ln2[i].x = fn0; ln2[i].y = fn1;
    }
    Sl = tree8(ln2);
    lino = vn;
  };
  auto fstep = [&]() {
#pragma unroll
    for (int i = 0; i < 4; ++i) e2[i] *= be2[i];
    const float esum = tree8(e2);
    const float dsum = esum + Sl;
    mem = fmaf(al, mem, fmaf(om, dsum, -sp));
    mmax = fmaxf(mmax, mem);
  };

  uint4 p0 = ld(0), p1 = ld(1);

  if (dir == 0) {
#pragma unroll 1
    for (int w = 0; w < SFRAMES; w += 2) {
      commit(p0); p0 = ld(w + 2);
#pragma unroll
      for (int t = 0; t < 10; ++t) fstep();
      commit(p1); p1 = ld(w + 3);
#pragma unroll
      for (int t = 0; t < 10; ++t) fstep();
    }
  } else {
    commit(p0); p0 = ld(2);
    fstep();
    commit(p1); p1 = ld(3);
#pragma unroll
    for (int t = 0; t < 9; ++t) fstep();
#pragma unroll 1
    for (int w = 1; w < 199; w += 2) {
      fstep();
      commit(p0); p0 = ld(w + 3);
#pragma unroll
      for (int t = 0; t < 9; ++t) fstep();
      fstep();
      commit(p1); p1 = ld(w + 4);
#pragma unroll
      for (int t = 0; t < 9; ++t) fstep();
    }
    fstep();
    commit(p0);
#pragma unroll
    for (int t = 0; t < 9; ++t) fstep();
  }

  const bool fail = (mmax > 1.0f);
  if (__any(fail ? 1 : 0) && threadIdx.x == 0) atomicOr(flag, 1u);
}

// ------------------------------------------------------- recurrent core ----
__device__ __forceinline__ void gload_lds16(const void* g, void* l) {
  __builtin_amdgcn_global_load_lds(
      (const __attribute__((address_space(1))) void*)g,
      (__attribute__((address_space(3))) void*)l, 16, 0, 0);
}

// grid = 64 chains (dir*32 + b), block = 64 (ONE wave). Early-exits when the
// cert kernel proved the whole sequence silent. Ring is NATURAL branch order:
// lane l, neuron group q reads position l*32 + q*8.
__global__ __launch_bounds__(64, 1) void snn_scan(
    const u16* __restrict__ LINH, const float* __restrict__ Wspk,
    const u16* __restrict__ OFFspk, const float* __restrict__ BETA,
    const float* __restrict__ ALPHA, float* __restrict__ FRAMES,
    const u32* __restrict__ flag)
{
  if (*flag == 0u) return;     // certified silent: outputs produced downstream

  const int chain = blockIdx.x;
  const int dir = chain >> 5;
  const int l = threadIdx.x;

  __shared__ __align__(16) u16 ring[4][NB];   // lin fp16 4-slot ring
  __shared__ __align__(16) float spkbuf[260]; // spikes; slots 256..259 stay 0

  {
    const float4 z4 = {0.f, 0.f, 0.f, 0.f};
    *reinterpret_cast<float4*>(&spkbuf[l * 4]) = z4;
    if (l == 0) *reinterpret_cast<float4*>(&spkbuf[256]) = z4;
    const uint4 zu = {0u, 0u, 0u, 0u};
    uint4* zz = reinterpret_cast<uint4*>(&ring[3][l * 32]);   // lin(-1) = 0
    zz[0] = zu; zz[1] = zu; zz[2] = zu; zz[3] = zu;
  }

  v2f e2[4][4], be2[4][4];
  float Sl[4] = {0.f, 0.f, 0.f, 0.f};
  float mem[4] = {0.f, 0.f, 0.f, 0.f};
  float sp[4] = {0.f, 0.f, 0.f, 0.f};
  float al[4], om[4];
#pragma unroll
  for (int q = 0; q < 4; ++q) {
    const v2f* bp = reinterpret_cast<const v2f*>(BETA + dir * NB + l * 32 + q * 8);
#pragma unroll
    for (int i = 0; i < 4; ++i) { be2[q][i] = bp[i]; e2[q][i] = (v2f){0.f, 0.f}; }
    al[q] = ALPHA[dir * HID + l * 4 + q];
    om[q] = 1.0f - al[q];
  }

  const u16* LB = LINH + (size_t)chain * NBLK * NB;
#pragma unroll
  for (int i = 0; i < 4; ++i) {
    gload_lds16(LB + 0 * NB + i * 512 + l * 8, &ring[0][i * 512]);
    gload_lds16(LB + 1 * NB + i * 512 + l * 8, &ring[1][i * 512]);
  }

  const float* wsp = Wspk + (size_t)dir * (NSYN * NB) + l * 32;
  const u16*  ofp = OFFspk + (size_t)dir * (NSYN * NB) + l * 32;
  float* frow = FRAMES + (size_t)chain * (SFRAMES * HID) + l * 4;

  int F = 0, c = 0;
  float mmax[4], facc[4];
  float4 pend = {0.f, 0.f, 0.f, 0.f};

  auto tree8 = [](const v2f v[4]) -> float {
    const v2f a = v[0] + v[1];
    const v2f b = v[2] + v[3];
    const v2f t = a + b;
    return t.x + t.y;
  };

  auto commit = [&](bool dopref) {
    const int sn = c & 3, so = (c + 3) & 3;
#pragma unroll
    for (int q = 0; q < 4; ++q) {
      const uint4 vn = *reinterpret_cast<const uint4*>(&ring[sn][l * 32 + q * 8]);
      const uint4 vo = *reinterpret_cast<const uint4*>(&ring[so][l * 32 + q * 8]);
      const _Float16* hn = reinterpret_cast<const _Float16*>(&vn);
      const _Float16* ho = reinterpret_cast<const _Float16*>(&vo);
      v2f ln2[4];
#pragma unroll
      for (int i = 0; i < 4; ++i) {
        const float fn0 = (float)hn[2 * i], fn1 = (float)hn[2 * i + 1];
        v2f dd; dd.x = (float)ho[2 * i] - fn0; dd.y = (float)ho[2 * i + 1] - fn1;
        e2[q][i] += dd;
        ln2[i].x = fn0; ln2[i].y = fn1;
      }
      Sl[q] = tree8(ln2);
    }
    if (dopref) {                       // prefetch 2 blocks ahead; slot disjoint
      const u16* src = LB + (size_t)(c + 2) * NB;
      u16* dst = &ring[(c + 2) & 3][0];
#pragma unroll
      for (int i = 0; i < 4; ++i)
        gload_lds16(src + i * 512 + l * 8, dst + i * 512);
    }
    ++c;
  };

  auto fstep = [&]() {
#pragma unroll
    for (int q = 0; q < 4; ++q)
#pragma unroll
      for (int i = 0; i < 4; ++i) e2[q][i] *= be2[q][i];
#pragma unroll
    for (int q = 0; q < 4; ++q) {
      const float esum = tree8(e2[q]);
      const float dsum = esum + Sl[q];
      mem[q] = fmaf(al[q], mem[q], fmaf(om[q], dsum, -sp[q]));
      mmax[q] = fmaxf(mmax[q], mem[q]);
    }
  };

  auto sstep = [&]() {
    if (__builtin_expect(F, 0)) {       // spikes live: exact gather
      float scv[4][8];
#pragma unroll
      for (int q = 0; q < 4; ++q)
#pragma unroll
        for (int j = 0; j < 8; ++j) scv[q][j] = 0.0f;
      const char* kb = reinterpret_cast<const char*>(&spkbuf[0]);
#pragma unroll 1
      for (int s = 0; s < NSYN; ++s) {
#pragma unroll
        for (int q = 0; q < 4; ++q) {
          float wv[8];
          *reinterpret_cast<float4*>(&wv[0]) =
              *reinterpret_cast<const float4*>(wsp + (size_t)s * NB + q * 8);
          *reinterpret_cast<float4*>(&wv[4]) =
              *reinterpret_cast<const float4*>(wsp + (size_t)s * NB + q * 8 + 4);
          const uint4 ov = *reinterpret_cast<const uint4*>(ofp + (size_t)s * NB + q * 8);
          const u16* of = reinterpret_cast<const u16*>(&ov);
#pragma unroll
          for (int j = 0; j < 8; ++j)
            scv[q][j] += wv[j] * *reinterpret_cast<const float*>(kb + of[j]);
        }
      }
#pragma unroll
      for (int q = 0; q < 4; ++q)
#pragma unroll
        for (int i = 0; i < 4; ++i) {
          v2f sc2; sc2.x = scv[q][2 * i]; sc2.y = scv[q][2 * i + 1];
          const v2f one = {1.0f, 1.0f};
          e2[q][i] = be2[q][i] * e2[q][i] + (one - be2[q][i]) * sc2;
        }
    } else {                            // silent: identical to fstep core
#pragma unroll
      for (int q = 0; q < 4; ++q)
#pragma unroll
        for (int i = 0; i < 4; ++i) e2[q][i] *= be2[q][i];
    }
    float ssum = 0.0f;
#pragma unroll
    for (int q = 0; q < 4; ++q) {
      const float esum = tree8(e2[q]);
      const float dsum = esum + Sl[q];
      mem[q] = fmaf(al[q], mem[q], fmaf(om[q], dsum, -sp[q]));
      sp[q] = (mem[q] > 1.0f) ? 1.0f : 0.0f;
      facc[q] += sp[q];
      ssum += sp[q];
    }
    const float4 sv = {sp[0], sp[1], sp[2], sp[3]};
    *reinterpret_cast<float4*>(&spkbuf[l * 4]) = sv;
    F = __any(ssum > 0.0f);
  };

#pragma unroll 1
  for (int w = 0; w < SFRAMES; ++w) {
    // save window-start state for possible slow redo
    v2f es[4][4]; float Sls[4], mems_[4], sps[4];
#pragma unroll
    for (int q = 0; q < 4; ++q) {
#pragma unroll
      for (int i = 0; i < 4; ++i) es[q][i] = e2[q][i];
      Sls[q] = Sl[q]; mems_[q] = mem[q]; sps[q] = sp[q];
    }
    const int cs = c;
    bool slow = (F != 0);
    bool prefed = false;

    if (!slow) {
      prefed = true;
      mmax[0] = mmax[1] = mmax[2] = mmax[3] = -1e30f;
      if (dir == 0) {
        VMW0(); commit(true);
        if (w) *reinterpret_cast<float4*>(frow + (w - 1) * HID) = pend;
#pragma unroll
        for (int t = 0; t < 10; ++t) fstep();
      } else {
        if (w == 0) { VMW0(); commit(true); }
        fstep();
        VMW0(); commit(true);
        if (w) *reinterpret_cast<float4*>(frow + (w - 1) * HID) = pend;
#pragma unroll
        for (int t = 0; t < 9; ++t) fstep();
      }
      const int viol = (mmax[0] > 1.0f) || (mmax[1] > 1.0f) ||
                       (mmax[2] > 1.0f) || (mmax[3] > 1.0f);
      slow = (__any(viol) != 0);
      if (!slow) {
        pend = (float4){0.f, 0.f, 0.f, 0.f};   // facc = 0 exactly
      } else {                                  // restore + redo
#pragma unroll
        for (int q = 0; q < 4; ++q) {
#pragma unroll
          for (int i = 0; i < 4; ++i) e2[q][i] = es[q][i];
          Sl[q] = Sls[q]; mem[q] = mems_[q]; sp[q] = sps[q];
        }
        c = cs;
      }
    }
    if (slow) {
      facc[0] = facc[1] = facc[2] = facc[3] = 0.0f;
      if (dir == 0) {
        VMW0(); commit(!prefed);
        if (w) *reinterpret_cast<float4*>(frow + (w - 1) * HID) = pend;
#pragma unroll 1
        for (int t = 0; t < 10; ++t) sstep();
      } else {
        if (w == 0) { VMW0(); commit(!prefed); }
        sstep();
        VMW0(); commit(!prefed);
        if (w) *reinterpret_cast<float4*>(frow + (w - 1) * HID) = pend;
#pragma unroll 1
        for (int t = 0; t < 9; ++t) sstep();
      }
      pend = (float4){facc[0] * 0.1f, facc[1] * 0.1f, facc[2] * 0.1f, facc[3] * 0.1f};
    }
  }
  *reinterpret_cast<float4*>(frow + (SFRAMES - 1) * HID) = pend;
}

// ------------------------------------------------------------- readout ----
__global__ __launch_bounds__(256) void ro_matmul(
    const float* __restrict__ FRAMES, const float* __restrict__ w_ro,
    const float* __restrict__ b_ro, float* __restrict__ Y,
    const u32* __restrict__ flag)
{
  if (*flag == 0u) return;   // certified silent: ro_scan uses b_ro directly

  const int bid = blockIdx.x;
  const int s = bid >> 1, b0 = (bid & 1) * 16;
  __shared__ float rowc[16 * 132];
  __shared__ float wlds[48 * 132];
  const int bb = threadIdx.x >> 4;
  const int oc = threadIdx.x & 15;
  const int o1 = oc + 16, o2 = oc + 32;
  float a0 = 0.f, a1 = 0.f, a2 = 0.f;
  const bool u2 = (o2 < OUTC);

#pragma unroll 1
  for (int kc = 0; kc < 4; ++kc) {
    for (int i = threadIdx.x; i < 16 * 128; i += 256) {
      const int rb = i >> 7, kk = i & 127;
      float v;
      if (kc < 2)
        v = FRAMES[((size_t)(b0 + rb) * SFRAMES + s) * HID + kc * 128 + kk];
      else
        v = FRAMES[((size_t)(32 + b0 + rb) * SFRAMES + (199 - s)) * HID + (kc - 2) * 128 + kk];
      rowc[rb * 132 + kk] = v;
    }
    for (int i = threadIdx.x; i < OUTC * 128; i += 256) {
      const int o = i >> 7, kk = i & 127;
      wlds[o * 132 + kk] = w_ro[(size_t)o * 512 + kc * 128 + kk];
    }
    __syncthreads();

    const float* rp = &rowc[bb * 132];
    const float* w0 = &wlds[oc * 132];
    const float* w1 = &wlds[o1 * 132];
    const float* w2 = &wlds[o2 * 132];
#pragma unroll 8
    for (int kk = 0; kk < 128; kk += 4) {
      const float4 a  = *reinterpret_cast<const float4*>(rp + kk);
      const float4 v0 = *reinterpret_cast<const float4*>(w0 + kk);
      const float4 v1 = *reinterpret_cast<const float4*>(w1 + kk);
      const float4 v2 = *reinterpret_cast<const float4*>(w2 + kk);
      a0 = fmaf(a.x, v0.x, fmaf(a.y, v0.y, fmaf(a.z, v0.z, fmaf(a.w, v0.w, a0))));
      a1 = fmaf(a.x, v1.x, fmaf(a.y, v1.y, fmaf(a.z, v1.z, fmaf(a.w, v1.w, a1))));
      if (u2)
        a2 = fmaf(a.x, v2.x, fmaf(a.y, v2.y, fmaf(a.z, v2.z, fmaf(a.w, v2.w, a2))));
    }
    __syncthreads();
  }

  float* yp = Y + ((size_t)s * 32 + b0 + bb) * OUTC;
  yp[oc] = a0 + b_ro[oc];
  yp[o1] = a1 + b_ro[o1];
  if (u2) yp[o2] = a2 + b_ro[o2];
}

__global__ __launch_bounds__(256) void ro_scan(
    const float* __restrict__ Y, const float* __restrict__ tau_ro,
    const float* __restrict__ b_ro, const int* __restrict__ labels,
    float* __restrict__ out, const u32* __restrict__ flag)
{
  const int b = blockIdx.x;
  const int tid = threadIdx.x;
  __shared__ float buf[SFRAMES * 40];
  __shared__ float lsum[256];

  if (*flag == 0u) {
    // certified silent: Y would be exactly b_ro (fmaf(0,w,0) chains stay 0)
    if (tid < OUTC) {
      const float ar = 1.0f / (1.0f + expf(-tau_ro[tid]));
      const float omr = 1.0f - ar;
      const float z = b_ro[tid];
      float m = 0.0f;
#pragma unroll 4
      for (int s = 0; s < SFRAMES; ++s) {
        m = ar * m + omr * z;
        buf[s * 40 + tid] = m;
      }
    }
  } else {
    for (int i = tid; i < SFRAMES * OUTC; i += 256) {
      const int s = i / OUTC, o = i - s * OUTC;
      buf[s * 40 + o] = Y[((size_t)s * 32 + b) * OUTC + o];
    }
    __syncthreads();
    if (tid < OUTC) {
      const float ar = 1.0f / (1.0f + expf(-tau_ro[tid]));
      const float omr = 1.0f - ar;
      float m = 0.0f;
#pragma unroll 4
      for (int s = 0; s < SFRAMES; ++s) {
        m = ar * m + omr * buf[s * 40 + tid];
        buf[s * 40 + tid] = m;
      }
    }
  }
  __syncthreads();

  float nacc = 0.0f;
  for (int s = tid; s < SFRAMES; s += 256) {
    float mx = -1e30f;
    for (int j = 0; j < OUTC; ++j) mx = fmaxf(mx, buf[s * 40 + j]);
    float se = 0.0f;
    for (int j = 0; j < OUTC; ++j) se += expf(buf[s * 40 + j] - mx);
    const float lse = logf(se);
    float* op = out + ((size_t)s * 32 + b) * OUTC;
    for (int j = 0; j < OUTC; ++j) op[j] = buf[s * 40 + j] - mx - lse;
    const int lab = labels[b * SFRAMES + s];
    nacc += -(buf[s * 40 + lab] - mx - lse);
  }
  lsum[tid] = nacc;
  __syncthreads();
  for (int off = 128; off > 0; off >>= 1) {
    if (tid < off) lsum[tid] += lsum[tid + off];
    __syncthreads();
  }
  if (tid == 0) atomicAdd(out + SFRAMES * 32 * OUTC, lsum[0] * (1.0f / 32.0f));
}

// -------------------------------------------------------------- launch ----
extern "C" void kernel_launch(void* const* d_in, const int* in_sizes, int n_in,
                              void* d_out, int out_size, void* d_ws, size_t ws_size,
                              hipStream_t stream)
{
  const float* x        = (const float*)d_in[0];
  const int*   labels   = (const int*)d_in[1];
  const float* w_fw     = (const float*)d_in[2];
  const float* b_fw     = (const float*)d_in[3];
  const float* tau_m_fw = (const float*)d_in[4];
  const float* tau_n_fw = (const float*)d_in[5];
  const float* mask_fw  = (const float*)d_in[6];
  const float* w_bw     = (const float*)d_in[7];
  const float* b_bw     = (const float*)d_in[8];
  const float* tau_m_bw = (const float*)d_in[9];
  const float* tau_n_bw = (const float*)d_in[10];
  const float* mask_bw  = (const float*)d_in[11];
  const float* w_ro     = (const float*)d_in[12];
  const float* b_ro     = (const float*)d_in[13];
  const float* tau_m_ro = (const float*)d_in[14];
  float* out = (float*)d_out;

  char* ws = (char*)d_ws;
  float* WiT    = (float*)(ws + WS_WIT);
  float* Wspk   = (float*)(ws + WS_WSPK);
  u16*   OFFspk = (u16*)(ws + WS_OFFSPK);
  float* CBIAS  = (float*)(ws + WS_CBIAS);
  float* BETA   = (float*)(ws + WS_BETA);
  float* ALPHA  = (float*)(ws + WS_ALPHA);
  float* FRAMES = (float*)(ws + WS_FRAMES);
  float* Y      = (float*)(ws + WS_Y);
  u16*   LINH   = (u16*)(ws + WS_LINH);
  u32*   FLAG   = (u32*)(ws + WS_FLAG);

  build_tables<<<1024, 256, 0, stream>>>(w_fw, b_fw, tau_n_fw, mask_fw,
                                         w_bw, b_bw, tau_n_bw, mask_bw,
                                         tau_m_fw, tau_m_bw,
                                         WiT, Wspk, OFFspk, CBIAS, BETA, ALPHA,
                                         FLAG, out + SFRAMES * 32 * OUTC);
  lin_gemm<<<1604, 512, 0, stream>>>(x, WiT, CBIAS, LINH);
  cert_scan<<<256, 64, 0, stream>>>(LINH, BETA, ALPHA, FLAG);
  snn_scan<<<64, 64, 0, stream>>>(LINH, Wspk, OFFspk, BETA, ALPHA, FRAMES, FLAG);
  ro_matmul<<<2 * SFRAMES, 256, 0, stream>>>(FRAMES, w_ro, b_ro, Y, FLAG);
  ro_scan<<<32, 256, 0, stream>>>(Y, tau_m_ro, b_ro, labels, out, FLAG);
}

// Round 12
// 106.814 us; speedup vs baseline: 10.0875x; 1.0661x over previous
//
#include <hip/hip_runtime.h>
#include <math.h>

typedef unsigned short u16;
typedef unsigned int u32;
typedef unsigned long long u64;
typedef float v2f __attribute__((ext_vector_type(2)));

#define NSYN 37
#define NB   2048
#define KS   296
#define NIN  39
#define TSTEPS 2000
#define SFRAMES 200
#define HID 256
#define OUTC 39
#define NBLK 204          // LIN blocks alloc'd per chain (fw uses 200, bw 201, pad)

// ws layout (byte offsets, 16B aligned)
#define WS_WIT    0u          // float [2][39][2048] dense input weights (transposed)
#define WS_WSPK   638976u     // float [2][37][2048] spike-synapse weights
#define WS_OFFSPK 1245184u    // u16   [2][37][2048] spike LDS byte offsets
#define WS_CBIAS  1548288u    // float [2][2048]     raw bias
#define WS_BETA   1564672u    // float [2][2048]
#define WS_ALPHA  1581056u    // float [2][256]
#define WS_FRAMES 1583104u    // float [2][32][200][256]
#define WS_Y      14690304u   // float [200][32][39]
#define WS_LINH   15688704u   // u16/fp16 [64 chains][204 blocks][2048] NATURAL branch order
#define WS_FLAG   69166080u   // u32: 0 = whole sequence certified silent

#define VMW0() asm volatile("s_waitcnt vmcnt(0)" ::: "memory")

// ---------------------------------------------------------------- setup ----
__global__ __launch_bounds__(256) void build_tables(
    const float* __restrict__ w_fw, const float* __restrict__ b_fw,
    const float* __restrict__ tau_n_fw, const float* __restrict__ mask_fw,
    const float* __restrict__ w_bw, const float* __restrict__ b_bw,
    const float* __restrict__ tau_n_bw, const float* __restrict__ mask_bw,
    const float* __restrict__ tau_m_fw, const float* __restrict__ tau_m_bw,
    float* __restrict__ WiT, float* __restrict__ Wspk, u16* __restrict__ OFFspk,
    float* __restrict__ CBIAS, float* __restrict__ BETA, float* __restrict__ ALPHA,
    u32* __restrict__ flagp, float* __restrict__ lossp)
{
  if (blockIdx.x == 0 && threadIdx.x == 0) { *flagp = 0u; *lossp = 0.0f; }
  const int row = blockIdx.x * 4 + (threadIdx.x >> 6);   // 0..4095
  const int l = threadIdx.x & 63;
  const int dir = row >> 11, r = row & (NB - 1);
  const float* w  = dir ? w_bw : w_fw;
  const float* mk = dir ? mask_bw : mask_fw;
  float* wit = WiT + (size_t)dir * (NIN * NB);
  float* wsp = Wspk + (size_t)dir * (NSYN * NB);
  u16*   osp = OFFspk + (size_t)dir * (NSYN * NB);
  const u64 ltm = (1ull << l) - 1ull;
  int sc = 0;
#pragma unroll
  for (int ch = 0; ch < 5; ++ch) {
    const int j = ch * 64 + l;
    const float m = (j < KS) ? mk[(size_t)r * KS + j] : 0.0f;
    const u64 bits = __ballot(m != 0.0f);
    const u64 sbits = (ch == 0) ? ((bits >> NIN) << NIN) : bits;  // entries j>=39
    if (ch == 0 && j < NIN) {
      wit[(size_t)j * NB + r] = (m != 0.0f) ? w[(size_t)r * KS + j] : 0.0f;
    } else if (m != 0.0f) {
      const int pos = sc + (int)__popcll(sbits & ltm);
      if (pos < NSYN) {
        wsp[(size_t)pos * NB + r] = w[(size_t)r * KS + j];
        osp[(size_t)pos * NB + r] = (u16)((j - NIN) * 4);
      }
    }
    sc += (int)__popcll(sbits);
  }
  for (int p = sc + l; p < NSYN; p += 64) {   // pad -> permanent-zero slot
    wsp[(size_t)p * NB + r] = 0.0f;
    osp[(size_t)p * NB + r] = (u16)(256 * 4);
  }
  if (l == 0) {
    const float* tn = dir ? tau_n_bw : tau_n_fw;
    const float* bb = dir ? b_bw : b_fw;
    BETA[dir * NB + r]  = 1.0f / (1.0f + expf(-tn[r]));
    CBIAS[dir * NB + r] = bb[r];
    if (r < HID) {
      const float* tm = dir ? tau_m_bw : tau_m_fw;
      ALPHA[dir * HID + r] = 1.0f / (1.0f + expf(-tm[r]));
    }
  }
}

// --------------------------------------------- per-frame input lin (fp16) ----
__global__ __launch_bounds__(512) void lin_gemm(
    const float* __restrict__ x, const float* __restrict__ WiT,
    const float* __restrict__ CBIAS, u16* __restrict__ LINH)
{
  const int bid = blockIdx.x;          // 0..1603
  const int cidx = bid >> 2, bg = bid & 3;
  const int dir = (cidx < 200) ? 0 : 1;
  const int c = (dir == 0) ? cidx : (cidx - 200);
  const int fr = (dir == 0) ? c : ((c == 0) ? 0 : 200 - c);
  const int b0 = bg * 8;
  const int t = threadIdx.x;

  __shared__ float xs[NIN * 8];        // xs[cc*8 + p]
  if (t < NIN * 8) {
    const int cc = t >> 3, p = t & 7;
    xs[t] = x[(size_t)(b0 + p) * (SFRAMES * NIN) + fr * NIN + cc];
  }
  __syncthreads();

  const float* wit = WiT + (size_t)dir * (NIN * NB) + t * 4;
  const float4 bv = *reinterpret_cast<const float4*>(CBIAS + dir * NB + t * 4);
  const float bias4[4] = {bv.x, bv.y, bv.z, bv.w};

  float acc[8][4];
#pragma unroll
  for (int p = 0; p < 8; ++p)
#pragma unroll
    for (int k = 0; k < 4; ++k) acc[p][k] = 0.0f;

#pragma unroll 3
  for (int cc = 0; cc < NIN; ++cc) {
    const float4 wv = *reinterpret_cast<const float4*>(wit + (size_t)cc * NB);
    const float4 s0 = *reinterpret_cast<const float4*>(&xs[cc * 8]);
    const float4 s1 = *reinterpret_cast<const float4*>(&xs[cc * 8 + 4]);
    const float sxa[8] = {s0.x, s0.y, s0.z, s0.w, s1.x, s1.y, s1.z, s1.w};
#pragma unroll
    for (int p = 0; p < 8; ++p) {
      acc[p][0] = fmaf(wv.x, sxa[p], acc[p][0]);
      acc[p][1] = fmaf(wv.y, sxa[p], acc[p][1]);
      acc[p][2] = fmaf(wv.z, sxa[p], acc[p][2]);
      acc[p][3] = fmaf(wv.w, sxa[p], acc[p][3]);
    }
  }

#pragma unroll
  for (int p = 0; p < 8; ++p) {
    u16* dst = LINH + ((size_t)(dir * 32 + b0 + p) * NBLK + c) * NB + t * 4;
    union { u16 h[4]; uint2 u; } pk;
#pragma unroll
    for (int k = 0; k < 4; ++k) {
      const _Float16 hv = (_Float16)(acc[p][k] + bias4[k]);
      pk.h[k] = *reinterpret_cast<const u16*>(&hv);
    }
    *reinterpret_cast<uint2*>(dst) = pk.u;
  }
}

// -------------------------------------------- parallel silent certificate ----
// One thread per (chain, neuron). BITWISE replay of the serial scan's fast
// path. 4-deep load pipeline: ~40 steps (~960 cyc) of prefetch cover vs
// ~900 cyc HBM latency (round-11's 1-deep = 240 cyc left commits stalled).
__global__ __launch_bounds__(64) void cert_scan(
    const u16* __restrict__ LINH, const float* __restrict__ BETA,
    const float* __restrict__ ALPHA, u32* __restrict__ flag)
{
  const int bid = blockIdx.x;
  const int chain = bid >> 2;
  const int dir = chain >> 5;
  const int nrn = (bid & 3) * 64 + threadIdx.x;   // 0..255

  v2f e2[4], be2[4];
  const v2f* bp = reinterpret_cast<const v2f*>(BETA + dir * NB + nrn * 8);
#pragma unroll
  for (int i = 0; i < 4; ++i) { be2[i] = bp[i]; e2[i] = (v2f){0.f, 0.f}; }
  const float al = ALPHA[dir * HID + nrn];
  const float om = 1.0f - al;
  const float sp = 0.0f;

  float Sl = 0.0f, mem = 0.0f, mmax = -1e30f;
  uint4 lino = {0u, 0u, 0u, 0u};

  const u16* LB = LINH + (size_t)chain * NBLK * NB;
  auto ld = [&](int c) {
    return *reinterpret_cast<const uint4*>(LB + (size_t)c * NB + nrn * 8);
  };
  auto tree8 = [](const v2f v[4]) -> float {
    const v2f a = v[0] + v[1];
    const v2f b = v[2] + v[3];
    const v2f t = a + b;
    return t.x + t.y;
  };
  auto commit = [&](uint4 vn) {
    const _Float16* hn = reinterpret_cast<const _Float16*>(&vn);
    const _Float16* ho = reinterpret_cast<const _Float16*>(&lino);
    v2f ln2[4];
#pragma unroll
    for (int i = 0; i < 4; ++i) {
      const float fn0 = (float)hn[2 * i], fn1 = (float)hn[2 * i + 1];
      v2f dd; dd.x = (float)ho[2 * i] - fn0; dd.y = (float)ho[2 * i + 1] - fn1;
      e2[i] += dd;
      ln2[i].x = fn0; ln2[i].y = fn1;
    }
    Sl = tree8(ln2);
    lino = vn;
  };
  auto fstep = [&]() {
#pragma unroll
    for (int i = 0; i < 4; ++i) e2[i] *= be2[i];
    const float esum = tree8(e2);
    const float dsum = esum + Sl;
    mem = fmaf(al, mem, fmaf(om, dsum, -sp));
    mmax = fmaxf(mmax, mem);
  };

  uint4 p0 = ld(0), p1 = ld(1), p2 = ld(2), p3 = ld(3);

  if (dir == 0) {
    // 200 windows, 4 per iteration; max prefetch index = 203 (alloc'd pad)
#pragma unroll 1
    for (int w = 0; w < SFRAMES; w += 4) {
      commit(p0); p0 = ld(w + 4);
#pragma unroll
      for (int t = 0; t < 10; ++t) fstep();
      commit(p1); p1 = ld(w + 5);
#pragma unroll
      for (int t = 0; t < 10; ++t) fstep();
      commit(p2); p2 = ld(w + 6);
#pragma unroll
      for (int t = 0; t < 10; ++t) fstep();
      commit(p3); p3 = ld(w + 7);
#pragma unroll
      for (int t = 0; t < 10; ++t) fstep();
    }
  } else {
    // window 0: commit b0; 1 step; commit b1; 9 steps
    commit(p0); p0 = ld(4);
    fstep();
    commit(p1); p1 = ld(5);
#pragma unroll
    for (int t = 0; t < 9; ++t) fstep();
    // windows 1..196 (49 x 4), committing b2..b197, prefetching to ld(201)
#pragma unroll 1
    for (int it = 0; it < 49; ++it) {
      const int base = 6 + it * 4;
      fstep();
      commit(p2); p2 = ld(base);
#pragma unroll
      for (int t = 0; t < 9; ++t) fstep();
      fstep();
      commit(p3); p3 = ld(base + 1);
#pragma unroll
      for (int t = 0; t < 9; ++t) fstep();
      fstep();
      commit(p0); p0 = ld(base + 2);
#pragma unroll
      for (int t = 0; t < 9; ++t) fstep();
      fstep();
      commit(p1); p1 = ld(base + 3);
#pragma unroll
      for (int t = 0; t < 9; ++t) fstep();
    }
    // windows 197,198,199: commit b198,b199,b200 (already in p2,p3,p0)
    fstep();
    commit(p2);
#pragma unroll
    for (int t = 0; t < 9; ++t) fstep();
    fstep();
    commit(p3);
#pragma unroll
    for (int t = 0; t < 9; ++t) fstep();
    fstep();
    commit(p0);
#pragma unroll
    for (int t = 0; t < 9; ++t) fstep();
  }

  const bool fail = (mmax > 1.0f);
  if (__any(fail ? 1 : 0) && threadIdx.x == 0) atomicOr(flag, 1u);
}

// ------------------------------------------------------- recurrent core ----
__device__ __forceinline__ void gload_lds16(const void* g, void* l) {
  __builtin_amdgcn_global_load_lds(
      (const __attribute__((address_space(1))) void*)g,
      (__attribute__((address_space(3))) void*)l, 16, 0, 0);
}

// grid = 64 chains, block = 64 (ONE wave). Early-exits when certified silent.
__global__ __launch_bounds__(64, 1) void snn_scan(
    const u16* __restrict__ LINH, const float* __restrict__ Wspk,
    const u16* __restrict__ OFFspk, const float* __restrict__ BETA,
    const float* __restrict__ ALPHA, float* __restrict__ FRAMES,
    const u32* __restrict__ flag)
{
  if (*flag == 0u) return;     // certified silent: outputs produced downstream

  const int chain = blockIdx.x;
  const int dir = chain >> 5;
  const int l = threadIdx.x;

  __shared__ __align__(16) u16 ring[4][NB];   // lin fp16 4-slot ring
  __shared__ __align__(16) float spkbuf[260]; // spikes; slots 256..259 stay 0

  {
    const float4 z4 = {0.f, 0.f, 0.f, 0.f};
    *reinterpret_cast<float4*>(&spkbuf[l * 4]) = z4;
    if (l == 0) *reinterpret_cast<float4*>(&spkbuf[256]) = z4;
    const uint4 zu = {0u, 0u, 0u, 0u};
    uint4* zz = reinterpret_cast<uint4*>(&ring[3][l * 32]);   // lin(-1) = 0
    zz[0] = zu; zz[1] = zu; zz[2] = zu; zz[3] = zu;
  }

  v2f e2[4][4], be2[4][4];
  float Sl[4] = {0.f, 0.f, 0.f, 0.f};
  float mem[4] = {0.f, 0.f, 0.f, 0.f};
  float sp[4] = {0.f, 0.f, 0.f, 0.f};
  float al[4], om[4];
#pragma unroll
  for (int q = 0; q < 4; ++q) {
    const v2f* bp = reinterpret_cast<const v2f*>(BETA + dir * NB + l * 32 + q * 8);
#pragma unroll
    for (int i = 0; i < 4; ++i) { be2[q][i] = bp[i]; e2[q][i] = (v2f){0.f, 0.f}; }
    al[q] = ALPHA[dir * HID + l * 4 + q];
    om[q] = 1.0f - al[q];
  }

  const u16* LB = LINH + (size_t)chain * NBLK * NB;
#pragma unroll
  for (int i = 0; i < 4; ++i) {
    gload_lds16(LB + 0 * NB + i * 512 + l * 8, &ring[0][i * 512]);
    gload_lds16(LB + 1 * NB + i * 512 + l * 8, &ring[1][i * 512]);
  }

  const float* wsp = Wspk + (size_t)dir * (NSYN * NB) + l * 32;
  const u16*  ofp = OFFspk + (size_t)dir * (NSYN * NB) + l * 32;
  float* frow = FRAMES + (size_t)chain * (SFRAMES * HID) + l * 4;

  int F = 0, c = 0;
  float mmax[4], facc[4];
  float4 pend = {0.f, 0.f, 0.f, 0.f};

  auto tree8 = [](const v2f v[4]) -> float {
    const v2f a = v[0] + v[1];
    const v2f b = v[2] + v[3];
    const v2f t = a + b;
    return t.x + t.y;
  };

  auto commit = [&](bool dopref) {
    const int sn = c & 3, so = (c + 3) & 3;
#pragma unroll
    for (int q = 0; q < 4; ++q) {
      const uint4 vn = *reinterpret_cast<const uint4*>(&ring[sn][l * 32 + q * 8]);
      const uint4 vo = *reinterpret_cast<const uint4*>(&ring[so][l * 32 + q * 8]);
      const _Float16* hn = reinterpret_cast<const _Float16*>(&vn);
      const _Float16* ho = reinterpret_cast<const _Float16*>(&vo);
      v2f ln2[4];
#pragma unroll
      for (int i = 0; i < 4; ++i) {
        const float fn0 = (float)hn[2 * i], fn1 = (float)hn[2 * i + 1];
        v2f dd; dd.x = (float)ho[2 * i] - fn0; dd.y = (float)ho[2 * i + 1] - fn1;
        e2[q][i] += dd;
        ln2[i].x = fn0; ln2[i].y = fn1;
      }
      Sl[q] = tree8(ln2);
    }
    if (dopref) {
      const u16* src = LB + (size_t)(c + 2) * NB;
      u16* dst = &ring[(c + 2) & 3][0];
#pragma unroll
      for (int i = 0; i < 4; ++i)
        gload_lds16(src + i * 512 + l * 8, dst + i * 512);
    }
    ++c;
  };

  auto fstep = [&]() {
#pragma unroll
    for (int q = 0; q < 4; ++q)
#pragma unroll
      for (int i = 0; i < 4; ++i) e2[q][i] *= be2[q][i];
#pragma unroll
    for (int q = 0; q < 4; ++q) {
      const float esum = tree8(e2[q]);
      const float dsum = esum + Sl[q];
      mem[q] = fmaf(al[q], mem[q], fmaf(om[q], dsum, -sp[q]));
      mmax[q] = fmaxf(mmax[q], mem[q]);
    }
  };

  auto sstep = [&]() {
    if (__builtin_expect(F, 0)) {       // spikes live: exact gather
      float scv[4][8];
#pragma unroll
      for (int q = 0; q < 4; ++q)
#pragma unroll
        for (int j = 0; j < 8; ++j) scv[q][j] = 0.0f;
      const char* kb = reinterpret_cast<const char*>(&spkbuf[0]);
#pragma unroll 1
      for (int s = 0; s < NSYN; ++s) {
#pragma unroll
        for (int q = 0; q < 4; ++q) {
          float wv[8];
          *reinterpret_cast<float4*>(&wv[0]) =
              *reinterpret_cast<const float4*>(wsp + (size_t)s * NB + q * 8);
          *reinterpret_cast<float4*>(&wv[4]) =
              *reinterpret_cast<const float4*>(wsp + (size_t)s * NB + q * 8 + 4);
          const uint4 ov = *reinterpret_cast<const uint4*>(ofp + (size_t)s * NB + q * 8);
          const u16* of = reinterpret_cast<const u16*>(&ov);
#pragma unroll
          for (int j = 0; j < 8; ++j)
            scv[q][j] += wv[j] * *reinterpret_cast<const float*>(kb + of[j]);
        }
      }
#pragma unroll
      for (int q = 0; q < 4; ++q)
#pragma unroll
        for (int i = 0; i < 4; ++i) {
          v2f sc2; sc2.x = scv[q][2 * i]; sc2.y = scv[q][2 * i + 1];
          const v2f one = {1.0f, 1.0f};
          e2[q][i] = be2[q][i] * e2[q][i] + (one - be2[q][i]) * sc2;
        }
    } else {                            // silent: identical to fstep core
#pragma unroll
      for (int q = 0; q < 4; ++q)
#pragma unroll
        for (int i = 0; i < 4; ++i) e2[q][i] *= be2[q][i];
    }
    float ssum = 0.0f;
#pragma unroll
    for (int q = 0; q < 4; ++q) {
      const float esum = tree8(e2[q]);
      const float dsum = esum + Sl[q];
      mem[q] = fmaf(al[q], mem[q], fmaf(om[q], dsum, -sp[q]));
      sp[q] = (mem[q] > 1.0f) ? 1.0f : 0.0f;
      facc[q] += sp[q];
      ssum += sp[q];
    }
    const float4 sv = {sp[0], sp[1], sp[2], sp[3]};
    *reinterpret_cast<float4*>(&spkbuf[l * 4]) = sv;
    F = __any(ssum > 0.0f);
  };

#pragma unroll 1
  for (int w = 0; w < SFRAMES; ++w) {
    v2f es[4][4]; float Sls[4], mems_[4], sps[4];
#pragma unroll
    for (int q = 0; q < 4; ++q) {
#pragma unroll
      for (int i = 0; i < 4; ++i) es[q][i] = e2[q][i];
      Sls[q] = Sl[q]; mems_[q] = mem[q]; sps[q] = sp[q];
    }
    const int cs = c;
    bool slow = (F != 0);
    bool prefed = false;

    if (!slow) {
      prefed = true;
      mmax[0] = mmax[1] = mmax[2] = mmax[3] = -1e30f;
      if (dir == 0) {
        VMW0(); commit(true);
        if (w) *reinterpret_cast<float4*>(frow + (w - 1) * HID) = pend;
#pragma unroll
        for (int t = 0; t < 10; ++t) fstep();
      } else {
        if (w == 0) { VMW0(); commit(true); }
        fstep();
        VMW0(); commit(true);
        if (w) *reinterpret_cast<float4*>(frow + (w - 1) * HID) = pend;
#pragma unroll
        for (int t = 0; t < 9; ++t) fstep();
      }
      const int viol = (mmax[0] > 1.0f) || (mmax[1] > 1.0f) ||
                       (mmax[2] > 1.0f) || (mmax[3] > 1.0f);
      slow = (__any(viol) != 0);
      if (!slow) {
        pend = (float4){0.f, 0.f, 0.f, 0.f};   // facc = 0 exactly
      } else {                                  // restore + redo
#pragma unroll
        for (int q = 0; q < 4; ++q) {
#pragma unroll
          for (int i = 0; i < 4; ++i) e2[q][i] = es[q][i];
          Sl[q] = Sls[q]; mem[q] = mems_[q]; sp[q] = sps[q];
        }
        c = cs;
      }
    }
    if (slow) {
      facc[0] = facc[1] = facc[2] = facc[3] = 0.0f;
      if (dir == 0) {
        VMW0(); commit(!prefed);
        if (w) *reinterpret_cast<float4*>(frow + (w - 1) * HID) = pend;
#pragma unroll 1
        for (int t = 0; t < 10; ++t) sstep();
      } else {
        if (w == 0) { VMW0(); commit(!prefed); }
        sstep();
        VMW0(); commit(!prefed);
        if (w) *reinterpret_cast<float4*>(frow + (w - 1) * HID) = pend;
#pragma unroll 1
        for (int t = 0; t < 9; ++t) sstep();
      }
      pend = (float4){facc[0] * 0.1f, facc[1] * 0.1f, facc[2] * 0.1f, facc[3] * 0.1f};
    }
  }
  *reinterpret_cast<float4*>(frow + (SFRAMES - 1) * HID) = pend;
}

// ------------------------------------------------------------- readout ----
__global__ __launch_bounds__(256) void ro_matmul(
    const float* __restrict__ FRAMES, const float* __restrict__ w_ro,
    const float* __restrict__ b_ro, float* __restrict__ Y,
    const u32* __restrict__ flag)
{
  if (*flag == 0u) return;   // certified silent: ro_scan uses b_ro directly

  const int bid = blockIdx.x;
  const int s = bid >> 1, b0 = (bid & 1) * 16;
  __shared__ float rowc[16 * 132];
  __shared__ float wlds[48 * 132];
  const int bb = threadIdx.x >> 4;
  const int oc = threadIdx.x & 15;
  const int o1 = oc + 16, o2 = oc + 32;
  float a0 = 0.f, a1 = 0.f, a2 = 0.f;
  const bool u2 = (o2 < OUTC);

#pragma unroll 1
  for (int kc = 0; kc < 4; ++kc) {
    for (int i = threadIdx.x; i < 16 * 128; i += 256) {
      const int rb = i >> 7, kk = i & 127;
      float v;
      if (kc < 2)
        v = FRAMES[((size_t)(b0 + rb) * SFRAMES + s) * HID + kc * 128 + kk];
      else
        v = FRAMES[((size_t)(32 + b0 + rb) * SFRAMES + (199 - s)) * HID + (kc - 2) * 128 + kk];
      rowc[rb * 132 + kk] = v;
    }
    for (int i = threadIdx.x; i < OUTC * 128; i += 256) {
      const int o = i >> 7, kk = i & 127;
      wlds[o * 132 + kk] = w_ro[(size_t)o * 512 + kc * 128 + kk];
    }
    __syncthreads();

    const float* rp = &rowc[bb * 132];
    const float* w0 = &wlds[oc * 132];
    const float* w1 = &wlds[o1 * 132];
    const float* w2 = &wlds[o2 * 132];
#pragma unroll 8
    for (int kk = 0; kk < 128; kk += 4) {
      const float4 a  = *reinterpret_cast<const float4*>(rp + kk);
      const float4 v0 = *reinterpret_cast<const float4*>(w0 + kk);
      const float4 v1 = *reinterpret_cast<const float4*>(w1 + kk);
      const float4 v2 = *reinterpret_cast<const float4*>(w2 + kk);
      a0 = fmaf(a.x, v0.x, fmaf(a.y, v0.y, fmaf(a.z, v0.z, fmaf(a.w, v0.w, a0))));
      a1 = fmaf(a.x, v1.x, fmaf(a.y, v1.y, fmaf(a.z, v1.z, fmaf(a.w, v1.w, a1))));
      if (u2)
        a2 = fmaf(a.x, v2.x, fmaf(a.y, v2.y, fmaf(a.z, v2.z, fmaf(a.w, v2.w, a2))));
    }
    __syncthreads();
  }

  float* yp = Y + ((size_t)s * 32 + b0 + bb) * OUTC;
  yp[oc] = a0 + b_ro[oc];
  yp[o1] = a1 + b_ro[o1];
  if (u2) yp[o2] = a2 + b_ro[o2];
}

__global__ __launch_bounds__(256) void ro_scan(
    const float* __restrict__ Y, const float* __restrict__ tau_ro,
    const float* __restrict__ b_ro, const int* __restrict__ labels,
    float* __restrict__ out, const u32* __restrict__ flag)
{
  const int b = blockIdx.x;
  const int tid = threadIdx.x;
  __shared__ float buf[SFRAMES * 40];
  __shared__ float lsum[256];

  if (*flag == 0u) {
    if (tid < OUTC) {
      const float ar = 1.0f / (1.0f + expf(-tau_ro[tid]));
      const float omr = 1.0f - ar;
      const float z = b_ro[tid];
      float m = 0.0f;
#pragma unroll 4
      for (int s = 0; s < SFRAMES; ++s) {
        m = ar * m + omr * z;
        buf[s * 40 + tid] = m;
      }
    }
  } else {
    for (int i = tid; i < SFRAMES * OUTC; i += 256) {
      const int s = i / OUTC, o = i - s * OUTC;
      buf[s * 40 + o] = Y[((size_t)s * 32 + b) * OUTC + o];
    }
    __syncthreads();
    if (tid < OUTC) {
      const float ar = 1.0f / (1.0f + expf(-tau_ro[tid]));
      const float omr = 1.0f - ar;
      float m = 0.0f;
#pragma unroll 4
      for (int s = 0; s < SFRAMES; ++s) {
        m = ar * m + omr * buf[s * 40 + tid];
        buf[s * 40 + tid] = m;
      }
    }
  }
  __syncthreads();

  float nacc = 0.0f;
  for (int s = tid; s < SFRAMES; s += 256) {
    float mx = -1e30f;
    for (int j = 0; j < OUTC; ++j) mx = fmaxf(mx, buf[s * 40 + j]);
    float se = 0.0f;
    for (int j = 0; j < OUTC; ++j) se += expf(buf[s * 40 + j] - mx);
    const float lse = logf(se);
    float* op = out + ((size_t)s * 32 + b) * OUTC;
    for (int j = 0; j < OUTC; ++j) op[j] = buf[s * 40 + j] - mx - lse;
    const int lab = labels[b * SFRAMES + s];
    nacc += -(buf[s * 40 + lab] - mx - lse);
  }
  lsum[tid] = nacc;
  __syncthreads();
  for (int off = 128; off > 0; off >>= 1) {
    if (tid < off) lsum[tid] += lsum[tid + off];
    __syncthreads();
  }
  if (tid == 0) atomicAdd(out + SFRAMES * 32 * OUTC, lsum[0] * (1.0f / 32.0f));
}

// -------------------------------------------------------------- launch ----
extern "C" void kernel_launch(void* const* d_in, const int* in_sizes, int n_in,
                              void* d_out, int out_size, void* d_ws, size_t ws_size,
                              hipStream_t stream)
{
  const float* x        = (const float*)d_in[0];
  const int*   labels   = (const int*)d_in[1];
  const float* w_fw     = (const float*)d_in[2];
  const float* b_fw     = (const float*)d_in[3];
  const float* tau_m_fw = (const float*)d_in[4];
  const float* tau_n_fw = (const float*)d_in[5];
  const float* mask_fw  = (const float*)d_in[6];
  const float* w_bw     = (const float*)d_in[7];
  const float* b_bw     = (const float*)d_in[8];
  const float* tau_m_bw = (const float*)d_in[9];
  const float* tau_n_bw = (const float*)d_in[10];
  const float* mask_bw  = (const float*)d_in[11];
  const float* w_ro     = (const float*)d_in[12];
  const float* b_ro     = (const float*)d_in[13];
  const float* tau_m_ro = (const float*)d_in[14];
  float* out = (float*)d_out;

  char* ws = (char*)d_ws;
  float* WiT    = (float*)(ws + WS_WIT);
  float* Wspk   = (float*)(ws + WS_WSPK);
  u16*   OFFspk = (u16*)(ws + WS_OFFSPK);
  float* CBIAS  = (float*)(ws + WS_CBIAS);
  float* BETA   = (float*)(ws + WS_BETA);
  float* ALPHA  = (float*)(ws + WS_ALPHA);
  float* FRAMES = (float*)(ws + WS_FRAMES);
  float* Y      = (float*)(ws + WS_Y);
  u16*   LINH   = (u16*)(ws + WS_LINH);
  u32*   FLAG   = (u32*)(ws + WS_FLAG);

  build_tables<<<1024, 256, 0, stream>>>(w_fw, b_fw, tau_n_fw, mask_fw,
                                         w_bw, b_bw, tau_n_bw, mask_bw,
                                         tau_m_fw, tau_m_bw,
                                         WiT, Wspk, OFFspk, CBIAS, BETA, ALPHA,
                                         FLAG, out + SFRAMES * 32 * OUTC);
  lin_gemm<<<1604, 512, 0, stream>>>(x, WiT, CBIAS, LINH);
  cert_scan<<<256, 64, 0, stream>>>(LINH, BETA, ALPHA, FLAG);
  snn_scan<<<64, 64, 0, stream>>>(LINH, Wspk, OFFspk, BETA, ALPHA, FRAMES, FLAG);
  ro_matmul<<<2 * SFRAMES, 256, 0, stream>>>(FRAMES, w_ro, b_ro, Y, FLAG);
  ro_scan<<<32, 256, 0, stream>>>(Y, tau_m_ro, b_ro, labels, out, FLAG);
}